// Round 1
// baseline (2875.294 us; speedup 1.0000x reference)
//
#include <hip/hip_runtime.h>

// ---------------------------------------------------------------------------
// GraphEncoderNetwork: GCNConv(mlp1 -> norm scatter -> mlp2) + pooled mlp_dag
// + global mlp. All fp32. N=200000, E=6400000, G=1000, IN=16, D=16.
// ---------------------------------------------------------------------------

__device__ __forceinline__ int lowerb(const int* __restrict__ b, int n, int v) {
  int lo = 0, hi = n;
  while (lo < hi) { int m = (lo + hi) >> 1; if (b[m] < v) lo = m + 1; else hi = m; }
  return lo;
}

// degree over col (message-source index); self-loop +1 added at use site
__global__ void k_deg(const int* __restrict__ col, unsigned* __restrict__ deg, int E) {
  int e = blockIdx.x * blockDim.x + threadIdx.x;
  if (e < E) atomicAdd(&deg[col[e]], 1u);
}

// mlp1 per node -> h[8]; store hs = dinv * h
__global__ void __launch_bounds__(256)
k_mlp1(const float* __restrict__ x, const unsigned* __restrict__ deg,
       const float* __restrict__ w1, const float* __restrict__ b1,
       const float* __restrict__ w2, const float* __restrict__ b2,
       const float* __restrict__ w3, const float* __restrict__ b3,
       float* __restrict__ hs, int N) {
  __shared__ float sW1[16 * 32], sB1[32], sW2[32 * 16], sB2[16], sW3[16 * 8], sB3[8];
  for (int t = threadIdx.x; t < 512; t += blockDim.x) { sW1[t] = w1[t]; sW2[t] = w2[t]; }
  for (int t = threadIdx.x; t < 128; t += blockDim.x) sW3[t] = w3[t];
  for (int t = threadIdx.x; t < 32; t += blockDim.x) sB1[t] = b1[t];
  for (int t = threadIdx.x; t < 16; t += blockDim.x) sB2[t] = b2[t];
  for (int t = threadIdx.x; t < 8; t += blockDim.x) sB3[t] = b3[t];
  __syncthreads();
  int i = blockIdx.x * blockDim.x + threadIdx.x;
  if (i >= N) return;

  float xin[16];
  const float4* xp = reinterpret_cast<const float4*>(x + (size_t)i * 16);
  #pragma unroll
  for (int q = 0; q < 4; q++) {
    float4 v = xp[q];
    xin[q * 4 + 0] = v.x; xin[q * 4 + 1] = v.y; xin[q * 4 + 2] = v.z; xin[q * 4 + 3] = v.w;
  }
  float h1[32];
  #pragma unroll
  for (int o = 0; o < 32; o++) {
    float s = sB1[o];
    #pragma unroll
    for (int k = 0; k < 16; k++) s = fmaf(xin[k], sW1[k * 32 + o], s);
    h1[o] = fmaxf(s, 0.f);
  }
  float h2[16];
  #pragma unroll
  for (int o = 0; o < 16; o++) {
    float s = sB2[o];
    #pragma unroll
    for (int k = 0; k < 32; k++) s = fmaf(h1[k], sW2[k * 16 + o], s);
    h2[o] = fmaxf(s, 0.f);
  }
  float dinv = rsqrtf((float)(deg[i] + 1u));  // +1 self-loop
  float o0[8];
  #pragma unroll
  for (int o = 0; o < 8; o++) {
    float s = sB3[o];
    #pragma unroll
    for (int k = 0; k < 16; k++) s = fmaf(h2[k], sW3[k * 8 + o], s);
    o0[o] = dinv * s;
  }
  float4* hp = reinterpret_cast<float4*>(hs + (size_t)i * 8);
  hp[0] = make_float4(o0[0], o0[1], o0[2], o0[3]);
  hp[1] = make_float4(o0[4], o0[5], o0[6], o0[7]);
}

// per-edge scatter: acc[row] += hs[col]   (self-loops excluded, added later)
__global__ void k_scatter(const int* __restrict__ row, const int* __restrict__ col,
                          const float* __restrict__ hs, float* __restrict__ acc, int E) {
  int e = blockIdx.x * blockDim.x + threadIdx.x;
  if (e >= E) return;
  int r = row[e], c = col[e];
  const float4* hp = reinterpret_cast<const float4*>(hs + (size_t)c * 8);
  float4 a = hp[0], b = hp[1];
  float* ap = acc + (size_t)r * 8;
  atomicAdd(ap + 0, a.x); atomicAdd(ap + 1, a.y);
  atomicAdd(ap + 2, a.z); atomicAdd(ap + 3, a.w);
  atomicAdd(ap + 4, b.x); atomicAdd(ap + 5, b.y);
  atomicAdd(ap + 6, b.z); atomicAdd(ap + 7, b.w);
}

// finalize agg, mlp2 -> x_node [N,16] written to d_out
__global__ void __launch_bounds__(256)
k_finalize(const float* __restrict__ hs, const float* __restrict__ acc,
           const unsigned* __restrict__ deg,
           const float* __restrict__ w1, const float* __restrict__ b1,
           const float* __restrict__ w2, const float* __restrict__ b2,
           const float* __restrict__ w3, const float* __restrict__ b3,
           float* __restrict__ xn, int N) {
  __shared__ float sW1[8 * 32], sB1[32], sW2[32 * 16], sB2[16], sW3[16 * 16], sB3[16];
  for (int t = threadIdx.x; t < 256; t += blockDim.x) { sW1[t] = w1[t]; sW3[t] = w3[t]; }
  for (int t = threadIdx.x; t < 512; t += blockDim.x) sW2[t] = w2[t];
  for (int t = threadIdx.x; t < 32; t += blockDim.x) sB1[t] = b1[t];
  for (int t = threadIdx.x; t < 16; t += blockDim.x) { sB2[t] = b2[t]; sB3[t] = b3[t]; }
  __syncthreads();
  int i = blockIdx.x * blockDim.x + threadIdx.x;
  if (i >= N) return;

  float dinv = rsqrtf((float)(deg[i] + 1u));
  float a[8];
  const float4* accp = reinterpret_cast<const float4*>(acc + (size_t)i * 8);
  const float4* hsp = reinterpret_cast<const float4*>(hs + (size_t)i * 8);
  float4 a0 = accp[0], a1 = accp[1], s0 = hsp[0], s1 = hsp[1];
  a[0] = dinv * (a0.x + s0.x); a[1] = dinv * (a0.y + s0.y);
  a[2] = dinv * (a0.z + s0.z); a[3] = dinv * (a0.w + s0.w);
  a[4] = dinv * (a1.x + s1.x); a[5] = dinv * (a1.y + s1.y);
  a[6] = dinv * (a1.z + s1.z); a[7] = dinv * (a1.w + s1.w);

  float h1[32];
  #pragma unroll
  for (int o = 0; o < 32; o++) {
    float s = sB1[o];
    #pragma unroll
    for (int k = 0; k < 8; k++) s = fmaf(a[k], sW1[k * 32 + o], s);
    h1[o] = fmaxf(s, 0.f);
  }
  float h2[16];
  #pragma unroll
  for (int o = 0; o < 16; o++) {
    float s = sB2[o];
    #pragma unroll
    for (int k = 0; k < 32; k++) s = fmaf(h1[k], sW2[k * 16 + o], s);
    h2[o] = fmaxf(s, 0.f);
  }
  float o0[16];
  #pragma unroll
  for (int o = 0; o < 16; o++) {
    float s = sB3[o];
    #pragma unroll
    for (int k = 0; k < 16; k++) s = fmaf(h2[k], sW3[k * 16 + o], s);
    o0[o] = s;
  }
  float4* op = reinterpret_cast<float4*>(xn + (size_t)i * 16);
  #pragma unroll
  for (int q = 0; q < 4; q++)
    op[q] = make_float4(o0[q * 4], o0[q * 4 + 1], o0[q * 4 + 2], o0[q * 4 + 3]);
}

// per-graph pooled sum of concat(x, x_node): one block per graph, batch sorted
__global__ void __launch_bounds__(256)
k_pool(const float* __restrict__ x, const float* __restrict__ xn,
       const int* __restrict__ batch, float* __restrict__ pool, int N) {
  int g = blockIdx.x;
  int lo = lowerb(batch, N, g);
  int hi = lowerb(batch, N, g + 1);
  int c = threadIdx.x & 31;   // channel 0..31
  int j = threadIdx.x >> 5;   // node group 0..7
  float s = 0.f;
  for (int n = lo + j; n < hi; n += 8) {
    s += (c < 16) ? x[(size_t)n * 16 + c] : xn[(size_t)n * 16 + (c - 16)];
  }
  __shared__ float red[8][33];
  red[j][c] = s;
  __syncthreads();
  if (threadIdx.x < 32) {
    float t = 0.f;
    #pragma unroll
    for (int q = 0; q < 8; q++) t += red[q][threadIdx.x];
    pool[(size_t)g * 32 + threadIdx.x] = t;
  }
}

// mlp_dag per graph (one thread per graph)
__global__ void __launch_bounds__(256)
k_dag(const float* __restrict__ pool,
      const float* __restrict__ w1, const float* __restrict__ b1,
      const float* __restrict__ w2, const float* __restrict__ b2,
      const float* __restrict__ w3, const float* __restrict__ b3,
      float* __restrict__ y, int G) {
  __shared__ float sW1[32 * 32], sB1[32], sW2[32 * 16], sB2[16], sW3[16 * 16], sB3[16];
  for (int t = threadIdx.x; t < 1024; t += blockDim.x) sW1[t] = w1[t];
  for (int t = threadIdx.x; t < 512; t += blockDim.x) sW2[t] = w2[t];
  for (int t = threadIdx.x; t < 256; t += blockDim.x) sW3[t] = w3[t];
  for (int t = threadIdx.x; t < 32; t += blockDim.x) sB1[t] = b1[t];
  for (int t = threadIdx.x; t < 16; t += blockDim.x) { sB2[t] = b2[t]; sB3[t] = b3[t]; }
  __syncthreads();
  int g = blockIdx.x * blockDim.x + threadIdx.x;
  if (g >= G) return;

  float in[32];
  const float4* pp = reinterpret_cast<const float4*>(pool + (size_t)g * 32);
  #pragma unroll
  for (int q = 0; q < 8; q++) {
    float4 v = pp[q];
    in[q * 4 + 0] = v.x; in[q * 4 + 1] = v.y; in[q * 4 + 2] = v.z; in[q * 4 + 3] = v.w;
  }
  float h1[32];
  #pragma unroll
  for (int o = 0; o < 32; o++) {
    float s = sB1[o];
    #pragma unroll
    for (int k = 0; k < 32; k++) s = fmaf(in[k], sW1[k * 32 + o], s);
    h1[o] = fmaxf(s, 0.f);
  }
  float h2[16];
  #pragma unroll
  for (int o = 0; o < 16; o++) {
    float s = sB2[o];
    #pragma unroll
    for (int k = 0; k < 32; k++) s = fmaf(h1[k], sW2[k * 16 + o], s);
    h2[o] = fmaxf(s, 0.f);
  }
  float o0[16];
  #pragma unroll
  for (int o = 0; o < 16; o++) {
    float s = sB3[o];
    #pragma unroll
    for (int k = 0; k < 16; k++) s = fmaf(h2[k], sW3[k * 16 + o], s);
    o0[o] = s;
  }
  float4* yp = reinterpret_cast<float4*>(y + (size_t)g * 16);
  #pragma unroll
  for (int q = 0; q < 4; q++)
    yp[q] = make_float4(o0[q * 4], o0[q * 4 + 1], o0[q * 4 + 2], o0[q * 4 + 3]);
}

// global: z = mlp_global(sum_g y[g]) — single block
__global__ void __launch_bounds__(256)
k_z(const float* __restrict__ y,
    const float* __restrict__ w1, const float* __restrict__ b1,
    const float* __restrict__ w2, const float* __restrict__ b2,
    const float* __restrict__ w3, const float* __restrict__ b3,
    float* __restrict__ z, int G) {
  __shared__ float red[16][17];
  __shared__ float sum[16], h1s[32], h2s[16];
  int t = threadIdx.x;
  int c = t & 15, j = t >> 4;
  float s = 0.f;
  for (int g = j; g < G; g += 16) s += y[(size_t)g * 16 + c];
  red[j][c] = s;
  __syncthreads();
  if (t < 16) {
    float v = 0.f;
    #pragma unroll
    for (int q = 0; q < 16; q++) v += red[q][t];
    sum[t] = v;
  }
  __syncthreads();
  if (t < 32) {
    float s1 = b1[t];
    #pragma unroll
    for (int k = 0; k < 16; k++) s1 = fmaf(sum[k], w1[k * 32 + t], s1);
    h1s[t] = fmaxf(s1, 0.f);
  }
  __syncthreads();
  if (t < 16) {
    float s2 = b2[t];
    #pragma unroll
    for (int k = 0; k < 32; k++) s2 = fmaf(h1s[k], w2[k * 16 + t], s2);
    h2s[t] = fmaxf(s2, 0.f);
  }
  __syncthreads();
  if (t < 16) {
    float s3 = b3[t];
    #pragma unroll
    for (int k = 0; k < 16; k++) s3 = fmaf(h2s[k], w3[k * 16 + t], s3);
    z[t] = s3;
  }
}

extern "C" void kernel_launch(void* const* d_in, const int* in_sizes, int n_in,
                              void* d_out, int out_size, void* d_ws, size_t ws_size,
                              hipStream_t stream) {
  const float* x = (const float*)d_in[0];
  const int* ei = (const int*)d_in[1];
  const int* batch = (const int*)d_in[2];
  // d_in[3] = num_graphs (device scalar, unused; G derived from out_size)
  const float* m1w1 = (const float*)d_in[4];  const float* m1b1 = (const float*)d_in[5];
  const float* m1w2 = (const float*)d_in[6];  const float* m1b2 = (const float*)d_in[7];
  const float* m1w3 = (const float*)d_in[8];  const float* m1b3 = (const float*)d_in[9];
  const float* m2w1 = (const float*)d_in[10]; const float* m2b1 = (const float*)d_in[11];
  const float* m2w2 = (const float*)d_in[12]; const float* m2b2 = (const float*)d_in[13];
  const float* m2w3 = (const float*)d_in[14]; const float* m2b3 = (const float*)d_in[15];
  const float* mdw1 = (const float*)d_in[16]; const float* mdb1 = (const float*)d_in[17];
  const float* mdw2 = (const float*)d_in[18]; const float* mdb2 = (const float*)d_in[19];
  const float* mdw3 = (const float*)d_in[20]; const float* mdb3 = (const float*)d_in[21];
  const float* mgw1 = (const float*)d_in[22]; const float* mgb1 = (const float*)d_in[23];
  const float* mgw2 = (const float*)d_in[24]; const float* mgb2 = (const float*)d_in[25];
  const float* mgw3 = (const float*)d_in[26]; const float* mgb3 = (const float*)d_in[27];

  int N = in_sizes[0] / 16;
  int E = in_sizes[1] / 2;
  int G = (out_size - N * 16 - 16) / 16;
  const int* rowp = ei;       // aggregation index
  const int* colp = ei + E;   // message source index

  // workspace layout: [deg N*4][acc N*32][hs N*32][pool G*128]
  char* ws = (char*)d_ws;
  unsigned* deg = (unsigned*)ws;
  float* acc = (float*)(ws + (size_t)N * 4);
  float* hs  = (float*)(ws + (size_t)N * 36);
  float* pool = (float*)(ws + (size_t)N * 68);

  hipMemsetAsync(ws, 0, (size_t)N * 36, stream);  // zero deg + acc

  float* xn = (float*)d_out;
  float* yv = xn + (size_t)N * 16;
  float* zv = yv + (size_t)G * 16;

  const int TB = 256;
  k_deg<<<(E + TB - 1) / TB, TB, 0, stream>>>(colp, deg, E);
  k_mlp1<<<(N + TB - 1) / TB, TB, 0, stream>>>(x, deg, m1w1, m1b1, m1w2, m1b2, m1w3, m1b3, hs, N);
  k_scatter<<<(E + TB - 1) / TB, TB, 0, stream>>>(rowp, colp, hs, acc, E);
  k_finalize<<<(N + TB - 1) / TB, TB, 0, stream>>>(hs, acc, deg, m2w1, m2b1, m2w2, m2b2, m2w3, m2b3, xn, N);
  k_pool<<<G, TB, 0, stream>>>(x, xn, batch, pool, N);
  k_dag<<<(G + TB - 1) / TB, TB, 0, stream>>>(pool, mdw1, mdb1, mdw2, mdb2, mdw3, mdb3, yv, G);
  k_z<<<1, TB, 0, stream>>>(yv, mgw1, mgb1, mgw2, mgb2, mgw3, mgb3, zv, G);
}

// Round 2
// 645.548 us; speedup vs baseline: 4.4540x; 4.4540x over previous
//
#include <hip/hip_runtime.h>

// ---------------------------------------------------------------------------
// GraphEncoderNetwork: GCNConv(mlp1 -> norm scatter -> mlp2) + pooled mlp_dag
// + global mlp. All fp32. N=200000, E=6400000, G=1000, IN=16, D=16.
//
// Round 2: replace 51.2M device-scope fp32 atomics (20 G/s wall, 2550 us)
// with dest-bucketed LDS accumulation:
//   bucket edges by row>>8 (atomic-light counting scatter), then one block
//   per 256-node bucket accumulates hs[col] into LDS via ds_add_f32 and
//   runs mlp2 inline. Degrees via the same bucketing machinery on col.
// ---------------------------------------------------------------------------

#define BSH 8               // bucket shift
#define BSZ 256             // nodes per bucket (== block size of k_agg/k_degb)
#define NBMAX 1024          // max buckets supported by scan/count LDS arrays

__device__ __forceinline__ int lowerb(const int* __restrict__ b, int n, int v) {
  int lo = 0, hi = n;
  while (lo < hi) { int m = (lo + hi) >> 1; if (b[m] < v) lo = m + 1; else hi = m; }
  return lo;
}

// ---------------- bucketing machinery (no fp32 global atomics) -------------

// count keys per bucket (key>>BSH), LDS-privatized, merge with few atomics
__global__ void __launch_bounds__(256)
k_count(const int* __restrict__ key, int E, int nb, unsigned* __restrict__ tot) {
  __shared__ unsigned h[NBMAX];
  int t = threadIdx.x;
  for (int i = t; i < nb; i += 256) h[i] = 0;
  __syncthreads();
  for (int i = blockIdx.x * blockDim.x + t; i < E; i += gridDim.x * blockDim.x)
    atomicAdd(&h[((unsigned)key[i]) >> BSH], 1u);
  __syncthreads();
  for (int i = t; i < nb; i += 256)
    if (h[i]) atomicAdd(&tot[i], h[i]);
}

// single-block exclusive scan of tot[nb] -> offs, cursor
__global__ void __launch_bounds__(NBMAX)
k_scan(const unsigned* __restrict__ tot, unsigned* __restrict__ offs,
       unsigned* __restrict__ cur, int nb) {
  __shared__ unsigned s[NBMAX];
  int t = threadIdx.x;
  unsigned own = (t < nb) ? tot[t] : 0u;
  s[t] = own;
  __syncthreads();
  for (int d = 1; d < NBMAX; d <<= 1) {
    unsigned v = (t >= d) ? s[t - d] : 0u;
    __syncthreads();
    s[t] += v;
    __syncthreads();
  }
  if (t < nb) { unsigned e = s[t] - own; offs[t] = e; cur[t] = e; }
}

// scatter edges into row-buckets; payload = (rel_row<<18)|col  (one u32)
__global__ void __launch_bounds__(256)
k_scat_row(const int* __restrict__ row, const int* __restrict__ col, int E, int nb,
           unsigned* __restrict__ cursor, unsigned* __restrict__ ebuf) {
  __shared__ unsigned h[NBMAX];
  __shared__ unsigned base[NBMAX];
  int t = threadIdx.x;
  int chunk = (E + gridDim.x - 1) / gridDim.x;
  int s = blockIdx.x * chunk, e = min(E, s + chunk);
  for (int i = t; i < nb; i += 256) h[i] = 0;
  __syncthreads();
  for (int i = s + t; i < e; i += 256)
    atomicAdd(&h[((unsigned)row[i]) >> BSH], 1u);
  __syncthreads();
  for (int i = t; i < nb; i += 256) {
    unsigned c = h[i];
    base[i] = c ? atomicAdd(&cursor[i], c) : 0u;
    h[i] = 0;
  }
  __syncthreads();
  for (int i = s + t; i < e; i += 256) {
    unsigned r = (unsigned)row[i];
    unsigned b = r >> BSH;
    unsigned p = base[b] + atomicAdd(&h[b], 1u);
    ebuf[p] = ((r & (BSZ - 1u)) << 18) | (unsigned)col[i];
  }
}

// scatter col keys into col-buckets; payload = rel_col (u16)
__global__ void __launch_bounds__(256)
k_scat_col(const int* __restrict__ col, int E, int nb,
           unsigned* __restrict__ cursor, unsigned short* __restrict__ ebuf2) {
  __shared__ unsigned h[NBMAX];
  __shared__ unsigned base[NBMAX];
  int t = threadIdx.x;
  int chunk = (E + gridDim.x - 1) / gridDim.x;
  int s = blockIdx.x * chunk, e = min(E, s + chunk);
  for (int i = t; i < nb; i += 256) h[i] = 0;
  __syncthreads();
  for (int i = s + t; i < e; i += 256)
    atomicAdd(&h[((unsigned)col[i]) >> BSH], 1u);
  __syncthreads();
  for (int i = t; i < nb; i += 256) {
    unsigned c = h[i];
    base[i] = c ? atomicAdd(&cursor[i], c) : 0u;
    h[i] = 0;
  }
  __syncthreads();
  for (int i = s + t; i < e; i += 256) {
    unsigned c = (unsigned)col[i];
    unsigned b = c >> BSH;
    unsigned p = base[b] + atomicAdd(&h[b], 1u);
    ebuf2[p] = (unsigned short)(c & (BSZ - 1u));
  }
}

// per-bucket degree histogram (LDS), direct write
__global__ void __launch_bounds__(BSZ)
k_degb(const unsigned short* __restrict__ eb, const unsigned* __restrict__ offs,
       const unsigned* __restrict__ tot, unsigned* __restrict__ deg, int N) {
  __shared__ unsigned cnt[BSZ];
  int b = blockIdx.x, t = threadIdx.x;
  cnt[t] = 0;
  __syncthreads();
  unsigned s = offs[b], n = tot[b];
  for (unsigned i = t; i < n; i += BSZ) atomicAdd(&cnt[eb[s + i]], 1u);
  __syncthreads();
  int node = b * BSZ + t;
  if (node < N) deg[node] = cnt[t];
}

// ---------------- node MLPs ------------------------------------------------

// mlp1 per node -> h[8]; store hs = dinv * h
__global__ void __launch_bounds__(256)
k_mlp1(const float* __restrict__ x, const unsigned* __restrict__ deg,
       const float* __restrict__ w1, const float* __restrict__ b1,
       const float* __restrict__ w2, const float* __restrict__ b2,
       const float* __restrict__ w3, const float* __restrict__ b3,
       float* __restrict__ hs, int N) {
  __shared__ float sW1[16 * 32], sB1[32], sW2[32 * 16], sB2[16], sW3[16 * 8], sB3[8];
  for (int t = threadIdx.x; t < 512; t += blockDim.x) { sW1[t] = w1[t]; sW2[t] = w2[t]; }
  for (int t = threadIdx.x; t < 128; t += blockDim.x) sW3[t] = w3[t];
  for (int t = threadIdx.x; t < 32; t += blockDim.x) sB1[t] = b1[t];
  for (int t = threadIdx.x; t < 16; t += blockDim.x) sB2[t] = b2[t];
  for (int t = threadIdx.x; t < 8; t += blockDim.x) sB3[t] = b3[t];
  __syncthreads();
  int i = blockIdx.x * blockDim.x + threadIdx.x;
  if (i >= N) return;

  float xin[16];
  const float4* xp = reinterpret_cast<const float4*>(x + (size_t)i * 16);
  #pragma unroll
  for (int q = 0; q < 4; q++) {
    float4 v = xp[q];
    xin[q * 4 + 0] = v.x; xin[q * 4 + 1] = v.y; xin[q * 4 + 2] = v.z; xin[q * 4 + 3] = v.w;
  }
  float h1[32];
  #pragma unroll
  for (int o = 0; o < 32; o++) {
    float s = sB1[o];
    #pragma unroll
    for (int k = 0; k < 16; k++) s = fmaf(xin[k], sW1[k * 32 + o], s);
    h1[o] = fmaxf(s, 0.f);
  }
  float h2[16];
  #pragma unroll
  for (int o = 0; o < 16; o++) {
    float s = sB2[o];
    #pragma unroll
    for (int k = 0; k < 32; k++) s = fmaf(h1[k], sW2[k * 16 + o], s);
    h2[o] = fmaxf(s, 0.f);
  }
  float dinv = rsqrtf((float)(deg[i] + 1u));  // +1 self-loop
  float o0[8];
  #pragma unroll
  for (int o = 0; o < 8; o++) {
    float s = sB3[o];
    #pragma unroll
    for (int k = 0; k < 16; k++) s = fmaf(h2[k], sW3[k * 8 + o], s);
    o0[o] = dinv * s;
  }
  float4* hp = reinterpret_cast<float4*>(hs + (size_t)i * 8);
  hp[0] = make_float4(o0[0], o0[1], o0[2], o0[3]);
  hp[1] = make_float4(o0[4], o0[5], o0[6], o0[7]);
}

// per-bucket accumulate (LDS ds_add_f32) + self-loop + mlp2 -> x_node
__global__ void __launch_bounds__(BSZ)
k_agg(const unsigned* __restrict__ ebuf, const unsigned* __restrict__ offs,
      const unsigned* __restrict__ tot,
      const float* __restrict__ hs, const unsigned* __restrict__ deg,
      const float* __restrict__ w1, const float* __restrict__ b1,
      const float* __restrict__ w2, const float* __restrict__ b2,
      const float* __restrict__ w3, const float* __restrict__ b3,
      float* __restrict__ xn, int N) {
  __shared__ float acc[8][BSZ];            // channel-major: bank = rel&31
  __shared__ float sW1[8 * 32], sB1[32], sW2[32 * 16], sB2[16], sW3[16 * 16], sB3[16];
  int t = threadIdx.x;
  for (int i = t; i < 256; i += BSZ) { sW1[i] = w1[i]; sW3[i] = w3[i]; }
  for (int i = t; i < 512; i += BSZ) sW2[i] = w2[i];
  if (t < 32) sB1[t] = b1[t];
  if (t < 16) { sB2[t] = b2[t]; sB3[t] = b3[t]; }
  #pragma unroll
  for (int c = 0; c < 8; c++) acc[c][t] = 0.f;
  __syncthreads();

  int b = blockIdx.x;
  unsigned s = offs[b], n = tot[b];
  for (unsigned i = t; i < n; i += BSZ) {
    unsigned p = ebuf[s + i];
    unsigned rel = p >> 18;
    unsigned c = p & 0x3FFFFu;
    const float4* hp = reinterpret_cast<const float4*>(hs + (size_t)c * 8);
    float4 a = hp[0], bb = hp[1];
    atomicAdd(&acc[0][rel], a.x); atomicAdd(&acc[1][rel], a.y);
    atomicAdd(&acc[2][rel], a.z); atomicAdd(&acc[3][rel], a.w);
    atomicAdd(&acc[4][rel], bb.x); atomicAdd(&acc[5][rel], bb.y);
    atomicAdd(&acc[6][rel], bb.z); atomicAdd(&acc[7][rel], bb.w);
  }
  __syncthreads();

  int node = b * BSZ + t;
  if (node >= N) return;
  float dinv = rsqrtf((float)(deg[node] + 1u));
  const float4* hsp = reinterpret_cast<const float4*>(hs + (size_t)node * 8);
  float4 s0 = hsp[0], s1 = hsp[1];
  float a[8];
  a[0] = dinv * (acc[0][t] + s0.x); a[1] = dinv * (acc[1][t] + s0.y);
  a[2] = dinv * (acc[2][t] + s0.z); a[3] = dinv * (acc[3][t] + s0.w);
  a[4] = dinv * (acc[4][t] + s1.x); a[5] = dinv * (acc[5][t] + s1.y);
  a[6] = dinv * (acc[6][t] + s1.z); a[7] = dinv * (acc[7][t] + s1.w);

  float h1[32];
  #pragma unroll
  for (int o = 0; o < 32; o++) {
    float v = sB1[o];
    #pragma unroll
    for (int k = 0; k < 8; k++) v = fmaf(a[k], sW1[k * 32 + o], v);
    h1[o] = fmaxf(v, 0.f);
  }
  float h2[16];
  #pragma unroll
  for (int o = 0; o < 16; o++) {
    float v = sB2[o];
    #pragma unroll
    for (int k = 0; k < 32; k++) v = fmaf(h1[k], sW2[k * 16 + o], v);
    h2[o] = fmaxf(v, 0.f);
  }
  float o0[16];
  #pragma unroll
  for (int o = 0; o < 16; o++) {
    float v = sB3[o];
    #pragma unroll
    for (int k = 0; k < 16; k++) v = fmaf(h2[k], sW3[k * 16 + o], v);
    o0[o] = v;
  }
  float4* op = reinterpret_cast<float4*>(xn + (size_t)node * 16);
  #pragma unroll
  for (int q = 0; q < 4; q++)
    op[q] = make_float4(o0[q * 4], o0[q * 4 + 1], o0[q * 4 + 2], o0[q * 4 + 3]);
}

// ---------------- pooling + graph/global MLPs ------------------------------

__global__ void __launch_bounds__(256)
k_pool(const float* __restrict__ x, const float* __restrict__ xn,
       const int* __restrict__ batch, float* __restrict__ pool, int N) {
  int g = blockIdx.x;
  int lo = lowerb(batch, N, g);
  int hi = lowerb(batch, N, g + 1);
  int c = threadIdx.x & 31;
  int j = threadIdx.x >> 5;
  float s = 0.f;
  for (int n = lo + j; n < hi; n += 8) {
    s += (c < 16) ? x[(size_t)n * 16 + c] : xn[(size_t)n * 16 + (c - 16)];
  }
  __shared__ float red[8][33];
  red[j][c] = s;
  __syncthreads();
  if (threadIdx.x < 32) {
    float t = 0.f;
    #pragma unroll
    for (int q = 0; q < 8; q++) t += red[q][threadIdx.x];
    pool[(size_t)g * 32 + threadIdx.x] = t;
  }
}

__global__ void __launch_bounds__(256)
k_dag(const float* __restrict__ pool,
      const float* __restrict__ w1, const float* __restrict__ b1,
      const float* __restrict__ w2, const float* __restrict__ b2,
      const float* __restrict__ w3, const float* __restrict__ b3,
      float* __restrict__ y, int G) {
  __shared__ float sW1[32 * 32], sB1[32], sW2[32 * 16], sB2[16], sW3[16 * 16], sB3[16];
  for (int t = threadIdx.x; t < 1024; t += blockDim.x) sW1[t] = w1[t];
  for (int t = threadIdx.x; t < 512; t += blockDim.x) sW2[t] = w2[t];
  for (int t = threadIdx.x; t < 256; t += blockDim.x) sW3[t] = w3[t];
  for (int t = threadIdx.x; t < 32; t += blockDim.x) sB1[t] = b1[t];
  for (int t = threadIdx.x; t < 16; t += blockDim.x) { sB2[t] = b2[t]; sB3[t] = b3[t]; }
  __syncthreads();
  int g = blockIdx.x * blockDim.x + threadIdx.x;
  if (g >= G) return;

  float in[32];
  const float4* pp = reinterpret_cast<const float4*>(pool + (size_t)g * 32);
  #pragma unroll
  for (int q = 0; q < 8; q++) {
    float4 v = pp[q];
    in[q * 4 + 0] = v.x; in[q * 4 + 1] = v.y; in[q * 4 + 2] = v.z; in[q * 4 + 3] = v.w;
  }
  float h1[32];
  #pragma unroll
  for (int o = 0; o < 32; o++) {
    float s = sB1[o];
    #pragma unroll
    for (int k = 0; k < 32; k++) s = fmaf(in[k], sW1[k * 32 + o], s);
    h1[o] = fmaxf(s, 0.f);
  }
  float h2[16];
  #pragma unroll
  for (int o = 0; o < 16; o++) {
    float s = sB2[o];
    #pragma unroll
    for (int k = 0; k < 32; k++) s = fmaf(h1[k], sW2[k * 16 + o], s);
    h2[o] = fmaxf(s, 0.f);
  }
  float o0[16];
  #pragma unroll
  for (int o = 0; o < 16; o++) {
    float s = sB3[o];
    #pragma unroll
    for (int k = 0; k < 16; k++) s = fmaf(h2[k], sW3[k * 16 + o], s);
    o0[o] = s;
  }
  float4* yp = reinterpret_cast<float4*>(y + (size_t)g * 16);
  #pragma unroll
  for (int q = 0; q < 4; q++)
    yp[q] = make_float4(o0[q * 4], o0[q * 4 + 1], o0[q * 4 + 2], o0[q * 4 + 3]);
}

__global__ void __launch_bounds__(256)
k_z(const float* __restrict__ y,
    const float* __restrict__ w1, const float* __restrict__ b1,
    const float* __restrict__ w2, const float* __restrict__ b2,
    const float* __restrict__ w3, const float* __restrict__ b3,
    float* __restrict__ z, int G) {
  __shared__ float red[16][17];
  __shared__ float sum[16], h1s[32], h2s[16];
  int t = threadIdx.x;
  int c = t & 15, j = t >> 4;
  float s = 0.f;
  for (int g = j; g < G; g += 16) s += y[(size_t)g * 16 + c];
  red[j][c] = s;
  __syncthreads();
  if (t < 16) {
    float v = 0.f;
    #pragma unroll
    for (int q = 0; q < 16; q++) v += red[q][t];
    sum[t] = v;
  }
  __syncthreads();
  if (t < 32) {
    float s1 = b1[t];
    #pragma unroll
    for (int k = 0; k < 16; k++) s1 = fmaf(sum[k], w1[k * 32 + t], s1);
    h1s[t] = fmaxf(s1, 0.f);
  }
  __syncthreads();
  if (t < 16) {
    float s2 = b2[t];
    #pragma unroll
    for (int k = 0; k < 32; k++) s2 = fmaf(h1s[k], w2[k * 16 + t], s2);
    h2s[t] = fmaxf(s2, 0.f);
  }
  __syncthreads();
  if (t < 16) {
    float s3 = b3[t];
    #pragma unroll
    for (int k = 0; k < 16; k++) s3 = fmaf(h2s[k], w3[k * 16 + t], s3);
    z[t] = s3;
  }
}

// ---------------- fallback (old atomic path, known-good) -------------------

__global__ void k_deg_atomic(const int* __restrict__ col, unsigned* __restrict__ deg, int E) {
  int e = blockIdx.x * blockDim.x + threadIdx.x;
  if (e < E) atomicAdd(&deg[col[e]], 1u);
}

__global__ void k_scatter_atomic(const int* __restrict__ row, const int* __restrict__ col,
                                 const float* __restrict__ hs, float* __restrict__ acc, int E) {
  int e = blockIdx.x * blockDim.x + threadIdx.x;
  if (e >= E) return;
  int r = row[e], c = col[e];
  const float4* hp = reinterpret_cast<const float4*>(hs + (size_t)c * 8);
  float4 a = hp[0], b = hp[1];
  float* ap = acc + (size_t)r * 8;
  atomicAdd(ap + 0, a.x); atomicAdd(ap + 1, a.y);
  atomicAdd(ap + 2, a.z); atomicAdd(ap + 3, a.w);
  atomicAdd(ap + 4, b.x); atomicAdd(ap + 5, b.y);
  atomicAdd(ap + 6, b.z); atomicAdd(ap + 7, b.w);
}

__global__ void __launch_bounds__(256)
k_finalize(const float* __restrict__ hs, const float* __restrict__ acc,
           const unsigned* __restrict__ deg,
           const float* __restrict__ w1, const float* __restrict__ b1,
           const float* __restrict__ w2, const float* __restrict__ b2,
           const float* __restrict__ w3, const float* __restrict__ b3,
           float* __restrict__ xn, int N) {
  __shared__ float sW1[8 * 32], sB1[32], sW2[32 * 16], sB2[16], sW3[16 * 16], sB3[16];
  for (int t = threadIdx.x; t < 256; t += blockDim.x) { sW1[t] = w1[t]; sW3[t] = w3[t]; }
  for (int t = threadIdx.x; t < 512; t += blockDim.x) sW2[t] = w2[t];
  for (int t = threadIdx.x; t < 32; t += blockDim.x) sB1[t] = b1[t];
  for (int t = threadIdx.x; t < 16; t += blockDim.x) { sB2[t] = b2[t]; sB3[t] = b3[t]; }
  __syncthreads();
  int i = blockIdx.x * blockDim.x + threadIdx.x;
  if (i >= N) return;

  float dinv = rsqrtf((float)(deg[i] + 1u));
  float a[8];
  const float4* accp = reinterpret_cast<const float4*>(acc + (size_t)i * 8);
  const float4* hsp = reinterpret_cast<const float4*>(hs + (size_t)i * 8);
  float4 a0 = accp[0], a1 = accp[1], s0 = hsp[0], s1 = hsp[1];
  a[0] = dinv * (a0.x + s0.x); a[1] = dinv * (a0.y + s0.y);
  a[2] = dinv * (a0.z + s0.z); a[3] = dinv * (a0.w + s0.w);
  a[4] = dinv * (a1.x + s1.x); a[5] = dinv * (a1.y + s1.y);
  a[6] = dinv * (a1.z + s1.z); a[7] = dinv * (a1.w + s1.w);

  float h1[32];
  #pragma unroll
  for (int o = 0; o < 32; o++) {
    float s = sB1[o];
    #pragma unroll
    for (int k = 0; k < 8; k++) s = fmaf(a[k], sW1[k * 32 + o], s);
    h1[o] = fmaxf(s, 0.f);
  }
  float h2[16];
  #pragma unroll
  for (int o = 0; o < 16; o++) {
    float s = sB2[o];
    #pragma unroll
    for (int k = 0; k < 32; k++) s = fmaf(h1[k], sW2[k * 16 + o], s);
    h2[o] = fmaxf(s, 0.f);
  }
  float o0[16];
  #pragma unroll
  for (int o = 0; o < 16; o++) {
    float s = sB3[o];
    #pragma unroll
    for (int k = 0; k < 16; k++) s = fmaf(h2[k], sW3[k * 16 + o], s);
    o0[o] = s;
  }
  float4* op = reinterpret_cast<float4*>(xn + (size_t)i * 16);
  #pragma unroll
  for (int q = 0; q < 4; q++)
    op[q] = make_float4(o0[q * 4], o0[q * 4 + 1], o0[q * 4 + 2], o0[q * 4 + 3]);
}

// ---------------------------------------------------------------------------

extern "C" void kernel_launch(void* const* d_in, const int* in_sizes, int n_in,
                              void* d_out, int out_size, void* d_ws, size_t ws_size,
                              hipStream_t stream) {
  const float* x = (const float*)d_in[0];
  const int* ei = (const int*)d_in[1];
  const int* batch = (const int*)d_in[2];
  const float* m1w1 = (const float*)d_in[4];  const float* m1b1 = (const float*)d_in[5];
  const float* m1w2 = (const float*)d_in[6];  const float* m1b2 = (const float*)d_in[7];
  const float* m1w3 = (const float*)d_in[8];  const float* m1b3 = (const float*)d_in[9];
  const float* m2w1 = (const float*)d_in[10]; const float* m2b1 = (const float*)d_in[11];
  const float* m2w2 = (const float*)d_in[12]; const float* m2b2 = (const float*)d_in[13];
  const float* m2w3 = (const float*)d_in[14]; const float* m2b3 = (const float*)d_in[15];
  const float* mdw1 = (const float*)d_in[16]; const float* mdb1 = (const float*)d_in[17];
  const float* mdw2 = (const float*)d_in[18]; const float* mdb2 = (const float*)d_in[19];
  const float* mdw3 = (const float*)d_in[20]; const float* mdb3 = (const float*)d_in[21];
  const float* mgw1 = (const float*)d_in[22]; const float* mgb1 = (const float*)d_in[23];
  const float* mgw2 = (const float*)d_in[24]; const float* mgb2 = (const float*)d_in[25];
  const float* mgw3 = (const float*)d_in[26]; const float* mgb3 = (const float*)d_in[27];

  int N = in_sizes[0] / 16;
  int E = in_sizes[1] / 2;
  int G = (out_size - N * 16 - 16) / 16;
  const int* rowp = ei;       // aggregation (destination) index
  const int* colp = ei + E;   // message source index

  float* xn = (float*)d_out;
  float* yv = xn + (size_t)N * 16;
  float* zv = yv + (size_t)G * 16;

  int nb = (N + BSZ - 1) / BSZ;

  // workspace layout (256B-aligned chunks)
  size_t off = 0;
  auto alloc = [&](size_t bytes) -> size_t {
    off = (off + 255) & ~(size_t)255;
    size_t o = off; off += bytes; return o;
  };
  char* ws = (char*)d_ws;
  size_t o_deg  = alloc((size_t)N * 4);
  size_t o_hs   = alloc((size_t)N * 32);
  size_t o_bkt  = alloc((size_t)6 * NBMAX * 4);   // tot_r,offs_r,cur_r,tot_c,offs_c,cur_c
  size_t o_eb   = alloc((size_t)E * 4);
  size_t o_eb2  = alloc((size_t)E * 2);
  size_t o_pool = alloc((size_t)G * 32 * 4);
  size_t need = off;

  bool bucketed = (ws_size >= need) && (nb <= NBMAX) && (N <= (1 << 18));

  if (bucketed) {
    unsigned* deg = (unsigned*)(ws + o_deg);
    float* hs = (float*)(ws + o_hs);
    unsigned* tot_r  = (unsigned*)(ws + o_bkt);
    unsigned* offs_r = tot_r + NBMAX;
    unsigned* cur_r  = tot_r + 2 * NBMAX;
    unsigned* tot_c  = tot_r + 3 * NBMAX;
    unsigned* offs_c = tot_r + 4 * NBMAX;
    unsigned* cur_c  = tot_r + 5 * NBMAX;
    unsigned* ebuf = (unsigned*)(ws + o_eb);
    unsigned short* ebuf2 = (unsigned short*)(ws + o_eb2);
    float* pool = (float*)(ws + o_pool);

    hipMemsetAsync(ws + o_bkt, 0, (size_t)6 * NBMAX * 4, stream);

    // degree path: bucket col -> per-bucket histogram
    k_count<<<512, 256, 0, stream>>>(colp, E, nb, tot_c);
    k_scan<<<1, NBMAX, 0, stream>>>(tot_c, offs_c, cur_c, nb);
    k_scat_col<<<256, 256, 0, stream>>>(colp, E, nb, cur_c, ebuf2);
    k_degb<<<nb, BSZ, 0, stream>>>(ebuf2, offs_c, tot_c, deg, N);

    // aggregation path: bucket edges by row
    k_count<<<512, 256, 0, stream>>>(rowp, E, nb, tot_r);
    k_scan<<<1, NBMAX, 0, stream>>>(tot_r, offs_r, cur_r, nb);
    k_scat_row<<<256, 256, 0, stream>>>(rowp, colp, E, nb, cur_r, ebuf);

    k_mlp1<<<(N + 255) / 256, 256, 0, stream>>>(x, deg, m1w1, m1b1, m1w2, m1b2, m1w3, m1b3, hs, N);
    k_agg<<<nb, BSZ, 0, stream>>>(ebuf, offs_r, tot_r, hs, deg,
                                  m2w1, m2b1, m2w2, m2b2, m2w3, m2b3, xn, N);

    k_pool<<<G, 256, 0, stream>>>(x, xn, batch, pool, N);
    k_dag<<<(G + 255) / 256, 256, 0, stream>>>(pool, mdw1, mdb1, mdw2, mdb2, mdw3, mdb3, yv, G);
    k_z<<<1, 256, 0, stream>>>(yv, mgw1, mgb1, mgw2, mgb2, mgw3, mgb3, zv, G);
  } else {
    // fallback: known-good atomic path
    unsigned* deg = (unsigned*)ws;
    float* acc = (float*)(ws + (size_t)N * 4);
    float* hs  = (float*)(ws + (size_t)N * 36);
    float* pool = (float*)(ws + (size_t)N * 68);

    hipMemsetAsync(ws, 0, (size_t)N * 36, stream);
    const int TB = 256;
    k_deg_atomic<<<(E + TB - 1) / TB, TB, 0, stream>>>(colp, deg, E);
    k_mlp1<<<(N + TB - 1) / TB, TB, 0, stream>>>(x, deg, m1w1, m1b1, m1w2, m1b2, m1w3, m1b3, hs, N);
    k_scatter_atomic<<<(E + TB - 1) / TB, TB, 0, stream>>>(rowp, colp, hs, acc, E);
    k_finalize<<<(N + TB - 1) / TB, TB, 0, stream>>>(hs, acc, deg, m2w1, m2b1, m2w2, m2b2, m2w3, m2b3, xn, N);
    k_pool<<<G, TB, 0, stream>>>(x, xn, batch, pool, N);
    k_dag<<<(G + TB - 1) / TB, TB, 0, stream>>>(pool, mdw1, mdb1, mdw2, mdb2, mdw3, mdb3, yv, G);
    k_z<<<1, TB, 0, stream>>>(yv, mgw1, mgb1, mgw2, mgb2, mgw3, mgb3, zv, G);
  }
}

// Round 3
// 631.537 us; speedup vs baseline: 4.5528x; 1.0222x over previous
//
#include <hip/hip_runtime.h>
#include <hip/hip_fp16.h>

// ---------------------------------------------------------------------------
// GraphEncoderNetwork: GCNConv(mlp1 -> norm scatter -> mlp2) + pooled mlp_dag
// + global mlp. All fp32. N=200000, E=6400000, G=1000, IN=16, D=16.
//
// Round 3: k_agg was latency-bound (occ 25%, 1 outstanding load/wave, fp32 hs
// table 6.4MB > 4MB per-XCD L2). Fixes: hs stored fp16x8 (3.2MB, L2-resident),
// BSZ 256->128 (2x blocks), 4-edge uint4-packed inner loop (4 independent
// gathers in flight), buckets padded to x4 edges for aligned vector loads.
// ---------------------------------------------------------------------------

#define BSH 7               // bucket shift
#define BSZ 128             // nodes per bucket
#define NBMAX 2048          // max buckets

__device__ __forceinline__ int lowerb(const int* __restrict__ b, int n, int v) {
  int lo = 0, hi = n;
  while (lo < hi) { int m = (lo + hi) >> 1; if (b[m] < v) lo = m + 1; else hi = m; }
  return lo;
}

// ---------------- bucketing machinery --------------------------------------

__global__ void __launch_bounds__(256)
k_count(const int* __restrict__ key, int E, int nb, unsigned* __restrict__ tot) {
  __shared__ unsigned h[NBMAX];
  int t = threadIdx.x;
  for (int i = t; i < nb; i += 256) h[i] = 0;
  __syncthreads();
  for (int i = blockIdx.x * blockDim.x + t; i < E; i += gridDim.x * blockDim.x)
    atomicAdd(&h[((unsigned)key[i]) >> BSH], 1u);
  __syncthreads();
  for (int i = t; i < nb; i += 256)
    if (h[i]) atomicAdd(&tot[i], h[i]);
}

// exclusive scan of pad-rounded tot[nb] -> offs, cur. 1024 thr, 2 elems each.
__global__ void __launch_bounds__(1024)
k_scan(const unsigned* __restrict__ tot, unsigned* __restrict__ offs,
       unsigned* __restrict__ cur, int nb, unsigned pm1) {
  __shared__ unsigned s[1024];
  int t = threadIdx.x;
  unsigned e0 = (2 * t < nb) ? ((tot[2 * t] + pm1) & ~pm1) : 0u;
  unsigned e1 = (2 * t + 1 < nb) ? ((tot[2 * t + 1] + pm1) & ~pm1) : 0u;
  unsigned sum = e0 + e1;
  s[t] = sum;
  __syncthreads();
  for (int d = 1; d < 1024; d <<= 1) {
    unsigned v = (t >= d) ? s[t - d] : 0u;
    __syncthreads();
    s[t] += v;
    __syncthreads();
  }
  unsigned ex = s[t] - sum;
  if (2 * t < nb)     { offs[2 * t] = ex;      cur[2 * t] = ex; }
  if (2 * t + 1 < nb) { offs[2 * t + 1] = ex + e0; cur[2 * t + 1] = ex + e0; }
}

// scatter edges into row-buckets; payload = (rel_row<<18)|col
__global__ void __launch_bounds__(256)
k_scat_row(const int* __restrict__ row, const int* __restrict__ col, int E, int nb,
           unsigned* __restrict__ cursor, unsigned* __restrict__ ebuf) {
  __shared__ unsigned h[NBMAX];
  __shared__ unsigned base[NBMAX];
  int t = threadIdx.x;
  int chunk = (E + gridDim.x - 1) / gridDim.x;
  int s = blockIdx.x * chunk, e = min(E, s + chunk);
  for (int i = t; i < nb; i += 256) h[i] = 0;
  __syncthreads();
  for (int i = s + t; i < e; i += 256)
    atomicAdd(&h[((unsigned)row[i]) >> BSH], 1u);
  __syncthreads();
  for (int i = t; i < nb; i += 256) {
    unsigned c = h[i];
    base[i] = c ? atomicAdd(&cursor[i], c) : 0u;
    h[i] = 0;
  }
  __syncthreads();
  for (int i = s + t; i < e; i += 256) {
    unsigned r = (unsigned)row[i];
    unsigned b = r >> BSH;
    unsigned p = base[b] + atomicAdd(&h[b], 1u);
    ebuf[p] = ((r & (BSZ - 1u)) << 18) | (unsigned)col[i];
  }
}

// scatter col keys into col-buckets; payload = rel_col (u16)
__global__ void __launch_bounds__(256)
k_scat_col(const int* __restrict__ col, int E, int nb,
           unsigned* __restrict__ cursor, unsigned short* __restrict__ ebuf2) {
  __shared__ unsigned h[NBMAX];
  __shared__ unsigned base[NBMAX];
  int t = threadIdx.x;
  int chunk = (E + gridDim.x - 1) / gridDim.x;
  int s = blockIdx.x * chunk, e = min(E, s + chunk);
  for (int i = t; i < nb; i += 256) h[i] = 0;
  __syncthreads();
  for (int i = s + t; i < e; i += 256)
    atomicAdd(&h[((unsigned)col[i]) >> BSH], 1u);
  __syncthreads();
  for (int i = t; i < nb; i += 256) {
    unsigned c = h[i];
    base[i] = c ? atomicAdd(&cursor[i], c) : 0u;
    h[i] = 0;
  }
  __syncthreads();
  for (int i = s + t; i < e; i += 256) {
    unsigned c = (unsigned)col[i];
    unsigned b = c >> BSH;
    unsigned p = base[b] + atomicAdd(&h[b], 1u);
    ebuf2[p] = (unsigned short)(c & (BSZ - 1u));
  }
}

// per-bucket degree histogram (LDS), direct write
__global__ void __launch_bounds__(256)
k_degb(const unsigned short* __restrict__ eb, const unsigned* __restrict__ offs,
       const unsigned* __restrict__ tot, unsigned* __restrict__ deg, int N) {
  __shared__ unsigned cnt[BSZ];
  int b = blockIdx.x, t = threadIdx.x;
  if (t < BSZ) cnt[t] = 0;
  __syncthreads();
  unsigned s = offs[b], n = tot[b];
  for (unsigned i = t; i < n; i += 256) atomicAdd(&cnt[eb[s + i]], 1u);
  __syncthreads();
  int node = b * BSZ + t;
  if (t < BSZ && node < N) deg[node] = cnt[t];
}

// ---------------- node MLPs ------------------------------------------------

// mlp1 per node -> h[8]; store hs16 = fp16x8 of dinv * h
__global__ void __launch_bounds__(256)
k_mlp1(const float* __restrict__ x, const unsigned* __restrict__ deg,
       const float* __restrict__ w1, const float* __restrict__ b1,
       const float* __restrict__ w2, const float* __restrict__ b2,
       const float* __restrict__ w3, const float* __restrict__ b3,
       uint4* __restrict__ hs16, int N) {
  __shared__ float sW1[16 * 32], sB1[32], sW2[32 * 16], sB2[16], sW3[16 * 8], sB3[8];
  for (int t = threadIdx.x; t < 512; t += blockDim.x) { sW1[t] = w1[t]; sW2[t] = w2[t]; }
  for (int t = threadIdx.x; t < 128; t += blockDim.x) sW3[t] = w3[t];
  for (int t = threadIdx.x; t < 32; t += blockDim.x) sB1[t] = b1[t];
  for (int t = threadIdx.x; t < 16; t += blockDim.x) sB2[t] = b2[t];
  for (int t = threadIdx.x; t < 8; t += blockDim.x) sB3[t] = b3[t];
  __syncthreads();
  int i = blockIdx.x * blockDim.x + threadIdx.x;
  if (i >= N) return;

  float xin[16];
  const float4* xp = reinterpret_cast<const float4*>(x + (size_t)i * 16);
  #pragma unroll
  for (int q = 0; q < 4; q++) {
    float4 v = xp[q];
    xin[q * 4 + 0] = v.x; xin[q * 4 + 1] = v.y; xin[q * 4 + 2] = v.z; xin[q * 4 + 3] = v.w;
  }
  float h1[32];
  #pragma unroll
  for (int o = 0; o < 32; o++) {
    float s = sB1[o];
    #pragma unroll
    for (int k = 0; k < 16; k++) s = fmaf(xin[k], sW1[k * 32 + o], s);
    h1[o] = fmaxf(s, 0.f);
  }
  float h2[16];
  #pragma unroll
  for (int o = 0; o < 16; o++) {
    float s = sB2[o];
    #pragma unroll
    for (int k = 0; k < 32; k++) s = fmaf(h1[k], sW2[k * 16 + o], s);
    h2[o] = fmaxf(s, 0.f);
  }
  float dinv = rsqrtf((float)(deg[i] + 1u));  // +1 self-loop
  float o0[8];
  #pragma unroll
  for (int o = 0; o < 8; o++) {
    float s = sB3[o];
    #pragma unroll
    for (int k = 0; k < 16; k++) s = fmaf(h2[k], sW3[k * 8 + o], s);
    o0[o] = dinv * s;
  }
  __half2 hh[4];
  #pragma unroll
  for (int q = 0; q < 4; q++) hh[q] = __floats2half2_rn(o0[2 * q], o0[2 * q + 1]);
  hs16[i] = *reinterpret_cast<const uint4*>(hh);
}

// per-bucket accumulate (LDS ds_add_f32, 4-edge ILP) + self-loop + mlp2
__global__ void __launch_bounds__(256)
k_agg(const unsigned* __restrict__ ebuf, const unsigned* __restrict__ offs,
      const unsigned* __restrict__ tot,
      const uint4* __restrict__ hs16, const unsigned* __restrict__ deg,
      const float* __restrict__ w1, const float* __restrict__ b1,
      const float* __restrict__ w2, const float* __restrict__ b2,
      const float* __restrict__ w3, const float* __restrict__ b3,
      float* __restrict__ xn, int N) {
  __shared__ float acc[8][BSZ];            // channel-major: bank = rel&31
  __shared__ float sW1[8 * 32], sB1[32], sW2[32 * 16], sB2[16], sW3[16 * 16], sB3[16];
  int t = threadIdx.x;
  for (int i = t; i < 256; i += 256) { sW1[i] = w1[i]; sW3[i] = w3[i]; }
  for (int i = t; i < 512; i += 256) sW2[i] = w2[i];
  if (t < 32) sB1[t] = b1[t];
  if (t < 16) { sB2[t] = b2[t]; sB3[t] = b3[t]; }
  for (int i = t; i < 8 * BSZ; i += 256) (&acc[0][0])[i] = 0.f;
  __syncthreads();

  int b = blockIdx.x;
  unsigned s = offs[b], n = tot[b];
  unsigned nr = (n + 3u) & ~3u;            // padded region is allocated
  for (unsigned i0 = 4 * t; i0 < nr; i0 += 1024) {
    uint4 pk = *reinterpret_cast<const uint4*>(ebuf + s + i0);  // 16B aligned
    unsigned rel[4]; uint4 g[4]; bool ok[4];
    #pragma unroll
    for (int j = 0; j < 4; j++) {
      unsigned p = (&pk.x)[j];
      ok[j] = (i0 + j) < n;
      rel[j] = p >> 18;
      unsigned c = p & 0x3FFFFu;
      if (ok[j]) g[j] = hs16[c];           // 4 independent 16B gathers in flight
    }
    #pragma unroll
    for (int j = 0; j < 4; j++) {
      if (!ok[j]) continue;
      const __half2* h2 = reinterpret_cast<const __half2*>(&g[j]);
      #pragma unroll
      for (int q = 0; q < 4; q++) {
        float2 f = __half22float2(h2[q]);
        atomicAdd(&acc[2 * q][rel[j]], f.x);
        atomicAdd(&acc[2 * q + 1][rel[j]], f.y);
      }
    }
  }
  __syncthreads();

  int node = b * BSZ + t;
  if (t >= BSZ || node >= N) return;
  float dinv = rsqrtf((float)(deg[node] + 1u));
  uint4 selfp = hs16[node];
  const __half2* sh = reinterpret_cast<const __half2*>(&selfp);
  float a[8];
  #pragma unroll
  for (int q = 0; q < 4; q++) {
    float2 f = __half22float2(sh[q]);
    a[2 * q]     = dinv * (acc[2 * q][t] + f.x);
    a[2 * q + 1] = dinv * (acc[2 * q + 1][t] + f.y);
  }

  float h1[32];
  #pragma unroll
  for (int o = 0; o < 32; o++) {
    float v = sB1[o];
    #pragma unroll
    for (int k = 0; k < 8; k++) v = fmaf(a[k], sW1[k * 32 + o], v);
    h1[o] = fmaxf(v, 0.f);
  }
  float h2v[16];
  #pragma unroll
  for (int o = 0; o < 16; o++) {
    float v = sB2[o];
    #pragma unroll
    for (int k = 0; k < 32; k++) v = fmaf(h1[k], sW2[k * 16 + o], v);
    h2v[o] = fmaxf(v, 0.f);
  }
  float o0[16];
  #pragma unroll
  for (int o = 0; o < 16; o++) {
    float v = sB3[o];
    #pragma unroll
    for (int k = 0; k < 16; k++) v = fmaf(h2v[k], sW3[k * 16 + o], v);
    o0[o] = v;
  }
  float4* op = reinterpret_cast<float4*>(xn + (size_t)node * 16);
  #pragma unroll
  for (int q = 0; q < 4; q++)
    op[q] = make_float4(o0[q * 4], o0[q * 4 + 1], o0[q * 4 + 2], o0[q * 4 + 3]);
}

// ---------------- pooling + graph/global MLPs ------------------------------

__global__ void __launch_bounds__(256)
k_pool(const float* __restrict__ x, const float* __restrict__ xn,
       const int* __restrict__ batch, float* __restrict__ pool, int N) {
  int g = blockIdx.x;
  int lo = lowerb(batch, N, g);
  int hi = lowerb(batch, N, g + 1);
  int c = threadIdx.x & 31;
  int j = threadIdx.x >> 5;
  float s = 0.f;
  for (int n = lo + j; n < hi; n += 8) {
    s += (c < 16) ? x[(size_t)n * 16 + c] : xn[(size_t)n * 16 + (c - 16)];
  }
  __shared__ float red[8][33];
  red[j][c] = s;
  __syncthreads();
  if (threadIdx.x < 32) {
    float t = 0.f;
    #pragma unroll
    for (int q = 0; q < 8; q++) t += red[q][threadIdx.x];
    pool[(size_t)g * 32 + threadIdx.x] = t;
  }
}

__global__ void __launch_bounds__(256)
k_dag(const float* __restrict__ pool,
      const float* __restrict__ w1, const float* __restrict__ b1,
      const float* __restrict__ w2, const float* __restrict__ b2,
      const float* __restrict__ w3, const float* __restrict__ b3,
      float* __restrict__ y, int G) {
  __shared__ float sW1[32 * 32], sB1[32], sW2[32 * 16], sB2[16], sW3[16 * 16], sB3[16];
  for (int t = threadIdx.x; t < 1024; t += blockDim.x) sW1[t] = w1[t];
  for (int t = threadIdx.x; t < 512; t += blockDim.x) sW2[t] = w2[t];
  for (int t = threadIdx.x; t < 256; t += blockDim.x) sW3[t] = w3[t];
  for (int t = threadIdx.x; t < 32; t += blockDim.x) sB1[t] = b1[t];
  for (int t = threadIdx.x; t < 16; t += blockDim.x) { sB2[t] = b2[t]; sB3[t] = b3[t]; }
  __syncthreads();
  int g = blockIdx.x * blockDim.x + threadIdx.x;
  if (g >= G) return;

  float in[32];
  const float4* pp = reinterpret_cast<const float4*>(pool + (size_t)g * 32);
  #pragma unroll
  for (int q = 0; q < 8; q++) {
    float4 v = pp[q];
    in[q * 4 + 0] = v.x; in[q * 4 + 1] = v.y; in[q * 4 + 2] = v.z; in[q * 4 + 3] = v.w;
  }
  float h1[32];
  #pragma unroll
  for (int o = 0; o < 32; o++) {
    float s = sB1[o];
    #pragma unroll
    for (int k = 0; k < 32; k++) s = fmaf(in[k], sW1[k * 32 + o], s);
    h1[o] = fmaxf(s, 0.f);
  }
  float h2[16];
  #pragma unroll
  for (int o = 0; o < 16; o++) {
    float s = sB2[o];
    #pragma unroll
    for (int k = 0; k < 32; k++) s = fmaf(h1[k], sW2[k * 16 + o], s);
    h2[o] = fmaxf(s, 0.f);
  }
  float o0[16];
  #pragma unroll
  for (int o = 0; o < 16; o++) {
    float s = sB3[o];
    #pragma unroll
    for (int k = 0; k < 16; k++) s = fmaf(h2[k], sW3[k * 16 + o], s);
    o0[o] = s;
  }
  float4* yp = reinterpret_cast<float4*>(y + (size_t)g * 16);
  #pragma unroll
  for (int q = 0; q < 4; q++)
    yp[q] = make_float4(o0[q * 4], o0[q * 4 + 1], o0[q * 4 + 2], o0[q * 4 + 3]);
}

__global__ void __launch_bounds__(256)
k_z(const float* __restrict__ y,
    const float* __restrict__ w1, const float* __restrict__ b1,
    const float* __restrict__ w2, const float* __restrict__ b2,
    const float* __restrict__ w3, const float* __restrict__ b3,
    float* __restrict__ z, int G) {
  __shared__ float red[16][17];
  __shared__ float sum[16], h1s[32], h2s[16];
  int t = threadIdx.x;
  int c = t & 15, j = t >> 4;
  float s = 0.f;
  for (int g = j; g < G; g += 16) s += y[(size_t)g * 16 + c];
  red[j][c] = s;
  __syncthreads();
  if (t < 16) {
    float v = 0.f;
    #pragma unroll
    for (int q = 0; q < 16; q++) v += red[q][t];
    sum[t] = v;
  }
  __syncthreads();
  if (t < 32) {
    float s1 = b1[t];
    #pragma unroll
    for (int k = 0; k < 16; k++) s1 = fmaf(sum[k], w1[k * 32 + t], s1);
    h1s[t] = fmaxf(s1, 0.f);
  }
  __syncthreads();
  if (t < 16) {
    float s2 = b2[t];
    #pragma unroll
    for (int k = 0; k < 32; k++) s2 = fmaf(h1s[k], w2[k * 16 + t], s2);
    h2s[t] = fmaxf(s2, 0.f);
  }
  __syncthreads();
  if (t < 16) {
    float s3 = b3[t];
    #pragma unroll
    for (int k = 0; k < 16; k++) s3 = fmaf(h2s[k], w3[k * 16 + t], s3);
    z[t] = s3;
  }
}

// ---------------- fallback (known-good atomic path) ------------------------

__global__ void k_deg_atomic(const int* __restrict__ col, unsigned* __restrict__ deg, int E) {
  int e = blockIdx.x * blockDim.x + threadIdx.x;
  if (e < E) atomicAdd(&deg[col[e]], 1u);
}

__global__ void __launch_bounds__(256)
k_mlp1f(const float* __restrict__ x, const unsigned* __restrict__ deg,
        const float* __restrict__ w1, const float* __restrict__ b1,
        const float* __restrict__ w2, const float* __restrict__ b2,
        const float* __restrict__ w3, const float* __restrict__ b3,
        float* __restrict__ hs, int N) {
  __shared__ float sW1[16 * 32], sB1[32], sW2[32 * 16], sB2[16], sW3[16 * 8], sB3[8];
  for (int t = threadIdx.x; t < 512; t += blockDim.x) { sW1[t] = w1[t]; sW2[t] = w2[t]; }
  for (int t = threadIdx.x; t < 128; t += blockDim.x) sW3[t] = w3[t];
  for (int t = threadIdx.x; t < 32; t += blockDim.x) sB1[t] = b1[t];
  for (int t = threadIdx.x; t < 16; t += blockDim.x) sB2[t] = b2[t];
  for (int t = threadIdx.x; t < 8; t += blockDim.x) sB3[t] = b3[t];
  __syncthreads();
  int i = blockIdx.x * blockDim.x + threadIdx.x;
  if (i >= N) return;
  float xin[16];
  const float4* xp = reinterpret_cast<const float4*>(x + (size_t)i * 16);
  #pragma unroll
  for (int q = 0; q < 4; q++) {
    float4 v = xp[q];
    xin[q * 4 + 0] = v.x; xin[q * 4 + 1] = v.y; xin[q * 4 + 2] = v.z; xin[q * 4 + 3] = v.w;
  }
  float h1[32];
  #pragma unroll
  for (int o = 0; o < 32; o++) {
    float s = sB1[o];
    #pragma unroll
    for (int k = 0; k < 16; k++) s = fmaf(xin[k], sW1[k * 32 + o], s);
    h1[o] = fmaxf(s, 0.f);
  }
  float h2[16];
  #pragma unroll
  for (int o = 0; o < 16; o++) {
    float s = sB2[o];
    #pragma unroll
    for (int k = 0; k < 32; k++) s = fmaf(h1[k], sW2[k * 16 + o], s);
    h2[o] = fmaxf(s, 0.f);
  }
  float dinv = rsqrtf((float)(deg[i] + 1u));
  float o0[8];
  #pragma unroll
  for (int o = 0; o < 8; o++) {
    float s = sB3[o];
    #pragma unroll
    for (int k = 0; k < 16; k++) s = fmaf(h2[k], sW3[k * 8 + o], s);
    o0[o] = dinv * s;
  }
  float4* hp = reinterpret_cast<float4*>(hs + (size_t)i * 8);
  hp[0] = make_float4(o0[0], o0[1], o0[2], o0[3]);
  hp[1] = make_float4(o0[4], o0[5], o0[6], o0[7]);
}

__global__ void k_scatter_atomic(const int* __restrict__ row, const int* __restrict__ col,
                                 const float* __restrict__ hs, float* __restrict__ acc, int E) {
  int e = blockIdx.x * blockDim.x + threadIdx.x;
  if (e >= E) return;
  int r = row[e], c = col[e];
  const float4* hp = reinterpret_cast<const float4*>(hs + (size_t)c * 8);
  float4 a = hp[0], b = hp[1];
  float* ap = acc + (size_t)r * 8;
  atomicAdd(ap + 0, a.x); atomicAdd(ap + 1, a.y);
  atomicAdd(ap + 2, a.z); atomicAdd(ap + 3, a.w);
  atomicAdd(ap + 4, b.x); atomicAdd(ap + 5, b.y);
  atomicAdd(ap + 6, b.z); atomicAdd(ap + 7, b.w);
}

__global__ void __launch_bounds__(256)
k_finalize(const float* __restrict__ hs, const float* __restrict__ acc,
           const unsigned* __restrict__ deg,
           const float* __restrict__ w1, const float* __restrict__ b1,
           const float* __restrict__ w2, const float* __restrict__ b2,
           const float* __restrict__ w3, const float* __restrict__ b3,
           float* __restrict__ xn, int N) {
  __shared__ float sW1[8 * 32], sB1[32], sW2[32 * 16], sB2[16], sW3[16 * 16], sB3[16];
  for (int t = threadIdx.x; t < 256; t += blockDim.x) { sW1[t] = w1[t]; sW3[t] = w3[t]; }
  for (int t = threadIdx.x; t < 512; t += blockDim.x) sW2[t] = w2[t];
  for (int t = threadIdx.x; t < 32; t += blockDim.x) sB1[t] = b1[t];
  for (int t = threadIdx.x; t < 16; t += blockDim.x) { sB2[t] = b2[t]; sB3[t] = b3[t]; }
  __syncthreads();
  int i = blockIdx.x * blockDim.x + threadIdx.x;
  if (i >= N) return;
  float dinv = rsqrtf((float)(deg[i] + 1u));
  float a[8];
  const float4* accp = reinterpret_cast<const float4*>(acc + (size_t)i * 8);
  const float4* hsp = reinterpret_cast<const float4*>(hs + (size_t)i * 8);
  float4 a0 = accp[0], a1 = accp[1], s0 = hsp[0], s1 = hsp[1];
  a[0] = dinv * (a0.x + s0.x); a[1] = dinv * (a0.y + s0.y);
  a[2] = dinv * (a0.z + s0.z); a[3] = dinv * (a0.w + s0.w);
  a[4] = dinv * (a1.x + s1.x); a[5] = dinv * (a1.y + s1.y);
  a[6] = dinv * (a1.z + s1.z); a[7] = dinv * (a1.w + s1.w);
  float h1[32];
  #pragma unroll
  for (int o = 0; o < 32; o++) {
    float s = sB1[o];
    #pragma unroll
    for (int k = 0; k < 8; k++) s = fmaf(a[k], sW1[k * 32 + o], s);
    h1[o] = fmaxf(s, 0.f);
  }
  float h2[16];
  #pragma unroll
  for (int o = 0; o < 16; o++) {
    float s = sB2[o];
    #pragma unroll
    for (int k = 0; k < 32; k++) s = fmaf(h1[k], sW2[k * 16 + o], s);
    h2[o] = fmaxf(s, 0.f);
  }
  float o0[16];
  #pragma unroll
  for (int o = 0; o < 16; o++) {
    float s = sB3[o];
    #pragma unroll
    for (int k = 0; k < 16; k++) s = fmaf(h2[k], sW3[k * 16 + o], s);
    o0[o] = s;
  }
  float4* op = reinterpret_cast<float4*>(xn + (size_t)i * 16);
  #pragma unroll
  for (int q = 0; q < 4; q++)
    op[q] = make_float4(o0[q * 4], o0[q * 4 + 1], o0[q * 4 + 2], o0[q * 4 + 3]);
}

// ---------------------------------------------------------------------------

extern "C" void kernel_launch(void* const* d_in, const int* in_sizes, int n_in,
                              void* d_out, int out_size, void* d_ws, size_t ws_size,
                              hipStream_t stream) {
  const float* x = (const float*)d_in[0];
  const int* ei = (const int*)d_in[1];
  const int* batch = (const int*)d_in[2];
  const float* m1w1 = (const float*)d_in[4];  const float* m1b1 = (const float*)d_in[5];
  const float* m1w2 = (const float*)d_in[6];  const float* m1b2 = (const float*)d_in[7];
  const float* m1w3 = (const float*)d_in[8];  const float* m1b3 = (const float*)d_in[9];
  const float* m2w1 = (const float*)d_in[10]; const float* m2b1 = (const float*)d_in[11];
  const float* m2w2 = (const float*)d_in[12]; const float* m2b2 = (const float*)d_in[13];
  const float* m2w3 = (const float*)d_in[14]; const float* m2b3 = (const float*)d_in[15];
  const float* mdw1 = (const float*)d_in[16]; const float* mdb1 = (const float*)d_in[17];
  const float* mdw2 = (const float*)d_in[18]; const float* mdb2 = (const float*)d_in[19];
  const float* mdw3 = (const float*)d_in[20]; const float* mdb3 = (const float*)d_in[21];
  const float* mgw1 = (const float*)d_in[22]; const float* mgb1 = (const float*)d_in[23];
  const float* mgw2 = (const float*)d_in[24]; const float* mgb2 = (const float*)d_in[25];
  const float* mgw3 = (const float*)d_in[26]; const float* mgb3 = (const float*)d_in[27];

  int N = in_sizes[0] / 16;
  int E = in_sizes[1] / 2;
  int G = (out_size - N * 16 - 16) / 16;
  const int* rowp = ei;       // aggregation (destination) index
  const int* colp = ei + E;   // message source index

  float* xn = (float*)d_out;
  float* yv = xn + (size_t)N * 16;
  float* zv = yv + (size_t)G * 16;

  int nb = (N + BSZ - 1) / BSZ;

  size_t off = 0;
  auto alloc = [&](size_t bytes) -> size_t {
    off = (off + 255) & ~(size_t)255;
    size_t o = off; off += bytes; return o;
  };
  char* ws = (char*)d_ws;
  size_t o_deg  = alloc((size_t)N * 4);
  size_t o_hs16 = alloc((size_t)N * 16);
  size_t o_bkt  = alloc((size_t)6 * NBMAX * 4);
  size_t o_eb   = alloc(((size_t)E + 4 * NBMAX) * 4);   // padded row buckets
  size_t o_eb2  = alloc((size_t)E * 2);
  size_t o_pool = alloc((size_t)G * 32 * 4);
  size_t need = off;

  bool bucketed = (ws_size >= need) && (nb <= NBMAX) && (N <= (1 << 18));

  if (bucketed) {
    unsigned* deg = (unsigned*)(ws + o_deg);
    uint4* hs16 = (uint4*)(ws + o_hs16);
    unsigned* tot_r  = (unsigned*)(ws + o_bkt);
    unsigned* offs_r = tot_r + NBMAX;
    unsigned* cur_r  = tot_r + 2 * NBMAX;
    unsigned* tot_c  = tot_r + 3 * NBMAX;
    unsigned* offs_c = tot_r + 4 * NBMAX;
    unsigned* cur_c  = tot_r + 5 * NBMAX;
    unsigned* ebuf = (unsigned*)(ws + o_eb);
    unsigned short* ebuf2 = (unsigned short*)(ws + o_eb2);
    float* pool = (float*)(ws + o_pool);

    hipMemsetAsync(ws + o_bkt, 0, (size_t)6 * NBMAX * 4, stream);

    // degree path: bucket col -> per-bucket histogram
    k_count<<<512, 256, 0, stream>>>(colp, E, nb, tot_c);
    k_scan<<<1, 1024, 0, stream>>>(tot_c, offs_c, cur_c, nb, 0u);
    k_scat_col<<<256, 256, 0, stream>>>(colp, E, nb, cur_c, ebuf2);
    k_degb<<<nb, 256, 0, stream>>>(ebuf2, offs_c, tot_c, deg, N);

    // aggregation path: bucket edges by row (pad buckets to x4 for uint4)
    k_count<<<512, 256, 0, stream>>>(rowp, E, nb, tot_r);
    k_scan<<<1, 1024, 0, stream>>>(tot_r, offs_r, cur_r, nb, 3u);
    k_scat_row<<<256, 256, 0, stream>>>(rowp, colp, E, nb, cur_r, ebuf);

    k_mlp1<<<(N + 255) / 256, 256, 0, stream>>>(x, deg, m1w1, m1b1, m1w2, m1b2, m1w3, m1b3, hs16, N);
    k_agg<<<nb, 256, 0, stream>>>(ebuf, offs_r, tot_r, hs16, deg,
                                  m2w1, m2b1, m2w2, m2b2, m2w3, m2b3, xn, N);

    k_pool<<<G, 256, 0, stream>>>(x, xn, batch, pool, N);
    k_dag<<<(G + 255) / 256, 256, 0, stream>>>(pool, mdw1, mdb1, mdw2, mdb2, mdw3, mdb3, yv, G);
    k_z<<<1, 256, 0, stream>>>(yv, mgw1, mgb1, mgw2, mgb2, mgw3, mgb3, zv, G);
  } else {
    unsigned* deg = (unsigned*)ws;
    float* acc = (float*)(ws + (size_t)N * 4);
    float* hs  = (float*)(ws + (size_t)N * 36);
    float* pool = (float*)(ws + (size_t)N * 68);

    hipMemsetAsync(ws, 0, (size_t)N * 36, stream);
    const int TB = 256;
    k_deg_atomic<<<(E + TB - 1) / TB, TB, 0, stream>>>(colp, deg, E);
    k_mlp1f<<<(N + TB - 1) / TB, TB, 0, stream>>>(x, deg, m1w1, m1b1, m1w2, m1b2, m1w3, m1b3, hs, N);
    k_scatter_atomic<<<(E + TB - 1) / TB, TB, 0, stream>>>(rowp, colp, hs, acc, E);
    k_finalize<<<(N + TB - 1) / TB, TB, 0, stream>>>(hs, acc, deg, m2w1, m2b1, m2w2, m2b2, m2w3, m2b3, xn, N);
    k_pool<<<G, TB, 0, stream>>>(x, xn, batch, pool, N);
    k_dag<<<(G + TB - 1) / TB, TB, 0, stream>>>(pool, mdw1, mdb1, mdw2, mdb2, mdw3, mdb3, yv, G);
    k_z<<<1, TB, 0, stream>>>(yv, mgw1, mgb1, mgw2, mgb2, mgw3, mgb3, zv, G);
  }
}

// Round 4
// 624.108 us; speedup vs baseline: 4.6070x; 1.0119x over previous
//
#include <hip/hip_runtime.h>
#include <hip/hip_fp16.h>

// ---------------------------------------------------------------------------
// GraphEncoderNetwork: GCNConv(mlp1 -> norm scatter -> mlp2) + pooled mlp_dag
// + global mlp. All fp32. N=200000, E=6400000, G=1000, IN=16, D=16.
//
// Round 4: k_agg was MLP-starved (4 outstanding gathers/wave, 600cy LLC
// latency -> 30 cy/gather). Now each thread issues its whole bucket share:
// 4 coalesced uint4 packed-edge loads + 16 independent hs16 gathers in
// flight, then 128 predicated LDS f32 atomics. Also: fused row+col bucket
// counting (one edge_index read) and fused 2-block scan.
// ---------------------------------------------------------------------------

#define BSH 7               // bucket shift
#define BSZ 128             // nodes per bucket
#define NBMAX 2048          // max buckets

__device__ __forceinline__ int lowerb(const int* __restrict__ b, int n, int v) {
  int lo = 0, hi = n;
  while (lo < hi) { int m = (lo + hi) >> 1; if (b[m] < v) lo = m + 1; else hi = m; }
  return lo;
}

// ---------------- bucketing machinery --------------------------------------

// fused: count row-keys and col-keys per bucket in one pass over edge_index
__global__ void __launch_bounds__(256)
k_count2(const int* __restrict__ row, const int* __restrict__ col, int E, int nb,
         unsigned* __restrict__ tot_r, unsigned* __restrict__ tot_c) {
  __shared__ unsigned hr[NBMAX];
  __shared__ unsigned hc[NBMAX];
  int t = threadIdx.x;
  for (int i = t; i < nb; i += 256) { hr[i] = 0; hc[i] = 0; }
  __syncthreads();
  for (int i = blockIdx.x * blockDim.x + t; i < E; i += gridDim.x * blockDim.x) {
    atomicAdd(&hr[((unsigned)row[i]) >> BSH], 1u);
    atomicAdd(&hc[((unsigned)col[i]) >> BSH], 1u);
  }
  __syncthreads();
  for (int i = t; i < nb; i += 256) {
    if (hr[i]) atomicAdd(&tot_r[i], hr[i]);
    if (hc[i]) atomicAdd(&tot_c[i], hc[i]);
  }
}

// fused scan: block 0 scans row arrays (pad x4), block 1 scans col arrays
__global__ void __launch_bounds__(1024)
k_scan2(const unsigned* __restrict__ tot_r, unsigned* __restrict__ offs_r,
        unsigned* __restrict__ cur_r,
        const unsigned* __restrict__ tot_c, unsigned* __restrict__ offs_c,
        unsigned* __restrict__ cur_c, int nb) {
  const unsigned* tot = blockIdx.x ? tot_c : tot_r;
  unsigned* offs = blockIdx.x ? offs_c : offs_r;
  unsigned* cur  = blockIdx.x ? cur_c  : cur_r;
  unsigned pm1 = blockIdx.x ? 0u : 3u;
  __shared__ unsigned s[1024];
  int t = threadIdx.x;
  unsigned e0 = (2 * t < nb) ? ((tot[2 * t] + pm1) & ~pm1) : 0u;
  unsigned e1 = (2 * t + 1 < nb) ? ((tot[2 * t + 1] + pm1) & ~pm1) : 0u;
  unsigned sum = e0 + e1;
  s[t] = sum;
  __syncthreads();
  for (int d = 1; d < 1024; d <<= 1) {
    unsigned v = (t >= d) ? s[t - d] : 0u;
    __syncthreads();
    s[t] += v;
    __syncthreads();
  }
  unsigned ex = s[t] - sum;
  if (2 * t < nb)     { offs[2 * t] = ex;          cur[2 * t] = ex; }
  if (2 * t + 1 < nb) { offs[2 * t + 1] = ex + e0; cur[2 * t + 1] = ex + e0; }
}

// scatter edges into row-buckets; payload = (rel_row<<18)|col
__global__ void __launch_bounds__(256)
k_scat_row(const int* __restrict__ row, const int* __restrict__ col, int E, int nb,
           unsigned* __restrict__ cursor, unsigned* __restrict__ ebuf) {
  __shared__ unsigned h[NBMAX];
  __shared__ unsigned base[NBMAX];
  int t = threadIdx.x;
  int chunk = (E + gridDim.x - 1) / gridDim.x;
  int s = blockIdx.x * chunk, e = min(E, s + chunk);
  for (int i = t; i < nb; i += 256) h[i] = 0;
  __syncthreads();
  for (int i = s + t; i < e; i += 256)
    atomicAdd(&h[((unsigned)row[i]) >> BSH], 1u);
  __syncthreads();
  for (int i = t; i < nb; i += 256) {
    unsigned c = h[i];
    base[i] = c ? atomicAdd(&cursor[i], c) : 0u;
    h[i] = 0;
  }
  __syncthreads();
  for (int i = s + t; i < e; i += 256) {
    unsigned r = (unsigned)row[i];
    unsigned b = r >> BSH;
    unsigned p = base[b] + atomicAdd(&h[b], 1u);
    ebuf[p] = ((r & (BSZ - 1u)) << 18) | (unsigned)col[i];
  }
}

// scatter col keys into col-buckets; payload = rel_col (u16)
__global__ void __launch_bounds__(256)
k_scat_col(const int* __restrict__ col, int E, int nb,
           unsigned* __restrict__ cursor, unsigned short* __restrict__ ebuf2) {
  __shared__ unsigned h[NBMAX];
  __shared__ unsigned base[NBMAX];
  int t = threadIdx.x;
  int chunk = (E + gridDim.x - 1) / gridDim.x;
  int s = blockIdx.x * chunk, e = min(E, s + chunk);
  for (int i = t; i < nb; i += 256) h[i] = 0;
  __syncthreads();
  for (int i = s + t; i < e; i += 256)
    atomicAdd(&h[((unsigned)col[i]) >> BSH], 1u);
  __syncthreads();
  for (int i = t; i < nb; i += 256) {
    unsigned c = h[i];
    base[i] = c ? atomicAdd(&cursor[i], c) : 0u;
    h[i] = 0;
  }
  __syncthreads();
  for (int i = s + t; i < e; i += 256) {
    unsigned c = (unsigned)col[i];
    unsigned b = c >> BSH;
    unsigned p = base[b] + atomicAdd(&h[b], 1u);
    ebuf2[p] = (unsigned short)(c & (BSZ - 1u));
  }
}

// per-bucket degree histogram (LDS), direct write
__global__ void __launch_bounds__(256)
k_degb(const unsigned short* __restrict__ eb, const unsigned* __restrict__ offs,
       const unsigned* __restrict__ tot, unsigned* __restrict__ deg, int N) {
  __shared__ unsigned cnt[BSZ];
  int b = blockIdx.x, t = threadIdx.x;
  if (t < BSZ) cnt[t] = 0;
  __syncthreads();
  unsigned s = offs[b], n = tot[b];
  for (unsigned i = t; i < n; i += 256) atomicAdd(&cnt[eb[s + i]], 1u);
  __syncthreads();
  int node = b * BSZ + t;
  if (t < BSZ && node < N) deg[node] = cnt[t];
}

// ---------------- node MLPs ------------------------------------------------

// mlp1 per node -> h[8]; store hs16 = fp16x8 of dinv * h
__global__ void __launch_bounds__(256)
k_mlp1(const float* __restrict__ x, const unsigned* __restrict__ deg,
       const float* __restrict__ w1, const float* __restrict__ b1,
       const float* __restrict__ w2, const float* __restrict__ b2,
       const float* __restrict__ w3, const float* __restrict__ b3,
       uint4* __restrict__ hs16, int N) {
  __shared__ float sW1[16 * 32], sB1[32], sW2[32 * 16], sB2[16], sW3[16 * 8], sB3[8];
  for (int t = threadIdx.x; t < 512; t += blockDim.x) { sW1[t] = w1[t]; sW2[t] = w2[t]; }
  for (int t = threadIdx.x; t < 128; t += blockDim.x) sW3[t] = w3[t];
  for (int t = threadIdx.x; t < 32; t += blockDim.x) sB1[t] = b1[t];
  for (int t = threadIdx.x; t < 16; t += blockDim.x) sB2[t] = b2[t];
  for (int t = threadIdx.x; t < 8; t += blockDim.x) sB3[t] = b3[t];
  __syncthreads();
  int i = blockIdx.x * blockDim.x + threadIdx.x;
  if (i >= N) return;

  float xin[16];
  const float4* xp = reinterpret_cast<const float4*>(x + (size_t)i * 16);
  #pragma unroll
  for (int q = 0; q < 4; q++) {
    float4 v = xp[q];
    xin[q * 4 + 0] = v.x; xin[q * 4 + 1] = v.y; xin[q * 4 + 2] = v.z; xin[q * 4 + 3] = v.w;
  }
  float h1[32];
  #pragma unroll
  for (int o = 0; o < 32; o++) {
    float s = sB1[o];
    #pragma unroll
    for (int k = 0; k < 16; k++) s = fmaf(xin[k], sW1[k * 32 + o], s);
    h1[o] = fmaxf(s, 0.f);
  }
  float h2[16];
  #pragma unroll
  for (int o = 0; o < 16; o++) {
    float s = sB2[o];
    #pragma unroll
    for (int k = 0; k < 32; k++) s = fmaf(h1[k], sW2[k * 16 + o], s);
    h2[o] = fmaxf(s, 0.f);
  }
  float dinv = rsqrtf((float)(deg[i] + 1u));  // +1 self-loop
  float o0[8];
  #pragma unroll
  for (int o = 0; o < 8; o++) {
    float s = sB3[o];
    #pragma unroll
    for (int k = 0; k < 16; k++) s = fmaf(h2[k], sW3[k * 8 + o], s);
    o0[o] = dinv * s;
  }
  __half2 hh[4];
  #pragma unroll
  for (int q = 0; q < 4; q++) hh[q] = __floats2half2_rn(o0[2 * q], o0[2 * q + 1]);
  hs16[i] = *reinterpret_cast<const uint4*>(hh);
}

// per-bucket accumulate: 16 gathers in flight per thread, LDS f32 atomics,
// then self-loop + mlp2 inline
__global__ void __launch_bounds__(256)
k_agg(const unsigned* __restrict__ ebuf, const unsigned* __restrict__ offs,
      const unsigned* __restrict__ tot,
      const uint4* __restrict__ hs16, const unsigned* __restrict__ deg,
      const float* __restrict__ w1, const float* __restrict__ b1,
      const float* __restrict__ w2, const float* __restrict__ b2,
      const float* __restrict__ w3, const float* __restrict__ b3,
      float* __restrict__ xn, int N) {
  __shared__ float acc[8][BSZ];            // channel-major: bank = rel&31
  __shared__ float sW1[8 * 32], sB1[32], sW2[32 * 16], sB2[16], sW3[16 * 16], sB3[16];
  int t = threadIdx.x;
  for (int i = t; i < 256; i += 256) { sW1[i] = w1[i]; sW3[i] = w3[i]; }
  for (int i = t; i < 512; i += 256) sW2[i] = w2[i];
  if (t < 32) sB1[t] = b1[t];
  if (t < 16) { sB2[t] = b2[t]; sB3[t] = b3[t]; }
  for (int i = t; i < 8 * BSZ; i += 256) (&acc[0][0])[i] = 0.f;
  __syncthreads();

  int b = blockIdx.x;
  unsigned s = offs[b], n = tot[b];
  unsigned nr = (n + 3u) & ~3u;            // padded region is allocated
  for (unsigned c0 = 0; c0 < nr; c0 += 4096) {
    // 4 coalesced uint4 packed-edge loads per thread (16 edges)
    uint4 pk[4];
    unsigned eidx[4];
    #pragma unroll
    for (int u = 0; u < 4; u++) {
      eidx[u] = c0 + 4 * (t + 256 * u);
      if (eidx[u] < nr)
        pk[u] = *reinterpret_cast<const uint4*>(ebuf + s + eidx[u]);
    }
    // 16 independent 16B gathers in flight
    uint4 g[16];
    #pragma unroll
    for (int u = 0; u < 4; u++) {
      #pragma unroll
      for (int j = 0; j < 4; j++) {
        if (eidx[u] + j < n)
          g[4 * u + j] = hs16[(&pk[u].x)[j] & 0x3FFFFu];
      }
    }
    // predicated LDS accumulation
    #pragma unroll
    for (int u = 0; u < 4; u++) {
      #pragma unroll
      for (int j = 0; j < 4; j++) {
        if (eidx[u] + j >= n) continue;
        unsigned rel = (&pk[u].x)[j] >> 18;
        const __half2* h2p = reinterpret_cast<const __half2*>(&g[4 * u + j]);
        #pragma unroll
        for (int q = 0; q < 4; q++) {
          float2 f = __half22float2(h2p[q]);
          atomicAdd(&acc[2 * q][rel], f.x);
          atomicAdd(&acc[2 * q + 1][rel], f.y);
        }
      }
    }
  }
  __syncthreads();

  int node = b * BSZ + t;
  if (t >= BSZ || node >= N) return;
  float dinv = rsqrtf((float)(deg[node] + 1u));
  uint4 selfp = hs16[node];
  const __half2* sh = reinterpret_cast<const __half2*>(&selfp);
  float a[8];
  #pragma unroll
  for (int q = 0; q < 4; q++) {
    float2 f = __half22float2(sh[q]);
    a[2 * q]     = dinv * (acc[2 * q][t] + f.x);
    a[2 * q + 1] = dinv * (acc[2 * q + 1][t] + f.y);
  }

  float h1[32];
  #pragma unroll
  for (int o = 0; o < 32; o++) {
    float v = sB1[o];
    #pragma unroll
    for (int k = 0; k < 8; k++) v = fmaf(a[k], sW1[k * 32 + o], v);
    h1[o] = fmaxf(v, 0.f);
  }
  float h2v[16];
  #pragma unroll
  for (int o = 0; o < 16; o++) {
    float v = sB2[o];
    #pragma unroll
    for (int k = 0; k < 32; k++) v = fmaf(h1[k], sW2[k * 16 + o], v);
    h2v[o] = fmaxf(v, 0.f);
  }
  float o0[16];
  #pragma unroll
  for (int o = 0; o < 16; o++) {
    float v = sB3[o];
    #pragma unroll
    for (int k = 0; k < 16; k++) v = fmaf(h2v[k], sW3[k * 16 + o], v);
    o0[o] = v;
  }
  float4* op = reinterpret_cast<float4*>(xn + (size_t)node * 16);
  #pragma unroll
  for (int q = 0; q < 4; q++)
    op[q] = make_float4(o0[q * 4], o0[q * 4 + 1], o0[q * 4 + 2], o0[q * 4 + 3]);
}

// ---------------- pooling + graph/global MLPs ------------------------------

__global__ void __launch_bounds__(256)
k_pool(const float* __restrict__ x, const float* __restrict__ xn,
       const int* __restrict__ batch, float* __restrict__ pool, int N) {
  int g = blockIdx.x;
  int lo = lowerb(batch, N, g);
  int hi = lowerb(batch, N, g + 1);
  int c = threadIdx.x & 31;
  int j = threadIdx.x >> 5;
  float s = 0.f;
  for (int n = lo + j; n < hi; n += 8) {
    s += (c < 16) ? x[(size_t)n * 16 + c] : xn[(size_t)n * 16 + (c - 16)];
  }
  __shared__ float red[8][33];
  red[j][c] = s;
  __syncthreads();
  if (threadIdx.x < 32) {
    float t = 0.f;
    #pragma unroll
    for (int q = 0; q < 8; q++) t += red[q][threadIdx.x];
    pool[(size_t)g * 32 + threadIdx.x] = t;
  }
}

__global__ void __launch_bounds__(256)
k_dag(const float* __restrict__ pool,
      const float* __restrict__ w1, const float* __restrict__ b1,
      const float* __restrict__ w2, const float* __restrict__ b2,
      const float* __restrict__ w3, const float* __restrict__ b3,
      float* __restrict__ y, int G) {
  __shared__ float sW1[32 * 32], sB1[32], sW2[32 * 16], sB2[16], sW3[16 * 16], sB3[16];
  for (int t = threadIdx.x; t < 1024; t += blockDim.x) sW1[t] = w1[t];
  for (int t = threadIdx.x; t < 512; t += blockDim.x) sW2[t] = w2[t];
  for (int t = threadIdx.x; t < 256; t += blockDim.x) sW3[t] = w3[t];
  for (int t = threadIdx.x; t < 32; t += blockDim.x) sB1[t] = b1[t];
  for (int t = threadIdx.x; t < 16; t += blockDim.x) { sB2[t] = b2[t]; sB3[t] = b3[t]; }
  __syncthreads();
  int g = blockIdx.x * blockDim.x + threadIdx.x;
  if (g >= G) return;

  float in[32];
  const float4* pp = reinterpret_cast<const float4*>(pool + (size_t)g * 32);
  #pragma unroll
  for (int q = 0; q < 8; q++) {
    float4 v = pp[q];
    in[q * 4 + 0] = v.x; in[q * 4 + 1] = v.y; in[q * 4 + 2] = v.z; in[q * 4 + 3] = v.w;
  }
  float h1[32];
  #pragma unroll
  for (int o = 0; o < 32; o++) {
    float s = sB1[o];
    #pragma unroll
    for (int k = 0; k < 32; k++) s = fmaf(in[k], sW1[k * 32 + o], s);
    h1[o] = fmaxf(s, 0.f);
  }
  float h2[16];
  #pragma unroll
  for (int o = 0; o < 16; o++) {
    float s = sB2[o];
    #pragma unroll
    for (int k = 0; k < 32; k++) s = fmaf(h1[k], sW2[k * 16 + o], s);
    h2[o] = fmaxf(s, 0.f);
  }
  float o0[16];
  #pragma unroll
  for (int o = 0; o < 16; o++) {
    float s = sB3[o];
    #pragma unroll
    for (int k = 0; k < 16; k++) s = fmaf(h2[k], sW3[k * 16 + o], s);
    o0[o] = s;
  }
  float4* yp = reinterpret_cast<float4*>(y + (size_t)g * 16);
  #pragma unroll
  for (int q = 0; q < 4; q++)
    yp[q] = make_float4(o0[q * 4], o0[q * 4 + 1], o0[q * 4 + 2], o0[q * 4 + 3]);
}

__global__ void __launch_bounds__(256)
k_z(const float* __restrict__ y,
    const float* __restrict__ w1, const float* __restrict__ b1,
    const float* __restrict__ w2, const float* __restrict__ b2,
    const float* __restrict__ w3, const float* __restrict__ b3,
    float* __restrict__ z, int G) {
  __shared__ float red[16][17];
  __shared__ float sum[16], h1s[32], h2s[16];
  int t = threadIdx.x;
  int c = t & 15, j = t >> 4;
  float s = 0.f;
  for (int g = j; g < G; g += 16) s += y[(size_t)g * 16 + c];
  red[j][c] = s;
  __syncthreads();
  if (t < 16) {
    float v = 0.f;
    #pragma unroll
    for (int q = 0; q < 16; q++) v += red[q][t];
    sum[t] = v;
  }
  __syncthreads();
  if (t < 32) {
    float s1 = b1[t];
    #pragma unroll
    for (int k = 0; k < 16; k++) s1 = fmaf(sum[k], w1[k * 32 + t], s1);
    h1s[t] = fmaxf(s1, 0.f);
  }
  __syncthreads();
  if (t < 16) {
    float s2 = b2[t];
    #pragma unroll
    for (int k = 0; k < 32; k++) s2 = fmaf(h1s[k], w2[k * 16 + t], s2);
    h2s[t] = fmaxf(s2, 0.f);
  }
  __syncthreads();
  if (t < 16) {
    float s3 = b3[t];
    #pragma unroll
    for (int k = 0; k < 16; k++) s3 = fmaf(h2s[k], w3[k * 16 + t], s3);
    z[t] = s3;
  }
}

// ---------------- fallback (known-good atomic path) ------------------------

__global__ void k_deg_atomic(const int* __restrict__ col, unsigned* __restrict__ deg, int E) {
  int e = blockIdx.x * blockDim.x + threadIdx.x;
  if (e < E) atomicAdd(&deg[col[e]], 1u);
}

__global__ void __launch_bounds__(256)
k_mlp1f(const float* __restrict__ x, const unsigned* __restrict__ deg,
        const float* __restrict__ w1, const float* __restrict__ b1,
        const float* __restrict__ w2, const float* __restrict__ b2,
        const float* __restrict__ w3, const float* __restrict__ b3,
        float* __restrict__ hs, int N) {
  __shared__ float sW1[16 * 32], sB1[32], sW2[32 * 16], sB2[16], sW3[16 * 8], sB3[8];
  for (int t = threadIdx.x; t < 512; t += blockDim.x) { sW1[t] = w1[t]; sW2[t] = w2[t]; }
  for (int t = threadIdx.x; t < 128; t += blockDim.x) sW3[t] = w3[t];
  for (int t = threadIdx.x; t < 32; t += blockDim.x) sB1[t] = b1[t];
  for (int t = threadIdx.x; t < 16; t += blockDim.x) sB2[t] = b2[t];
  for (int t = threadIdx.x; t < 8; t += blockDim.x) sB3[t] = b3[t];
  __syncthreads();
  int i = blockIdx.x * blockDim.x + threadIdx.x;
  if (i >= N) return;
  float xin[16];
  const float4* xp = reinterpret_cast<const float4*>(x + (size_t)i * 16);
  #pragma unroll
  for (int q = 0; q < 4; q++) {
    float4 v = xp[q];
    xin[q * 4 + 0] = v.x; xin[q * 4 + 1] = v.y; xin[q * 4 + 2] = v.z; xin[q * 4 + 3] = v.w;
  }
  float h1[32];
  #pragma unroll
  for (int o = 0; o < 32; o++) {
    float s = sB1[o];
    #pragma unroll
    for (int k = 0; k < 16; k++) s = fmaf(xin[k], sW1[k * 32 + o], s);
    h1[o] = fmaxf(s, 0.f);
  }
  float h2[16];
  #pragma unroll
  for (int o = 0; o < 16; o++) {
    float s = sB2[o];
    #pragma unroll
    for (int k = 0; k < 32; k++) s = fmaf(h1[k], sW2[k * 16 + o], s);
    h2[o] = fmaxf(s, 0.f);
  }
  float dinv = rsqrtf((float)(deg[i] + 1u));
  float o0[8];
  #pragma unroll
  for (int o = 0; o < 8; o++) {
    float s = sB3[o];
    #pragma unroll
    for (int k = 0; k < 16; k++) s = fmaf(h2[k], sW3[k * 8 + o], s);
    o0[o] = dinv * s;
  }
  float4* hp = reinterpret_cast<float4*>(hs + (size_t)i * 8);
  hp[0] = make_float4(o0[0], o0[1], o0[2], o0[3]);
  hp[1] = make_float4(o0[4], o0[5], o0[6], o0[7]);
}

__global__ void k_scatter_atomic(const int* __restrict__ row, const int* __restrict__ col,
                                 const float* __restrict__ hs, float* __restrict__ acc, int E) {
  int e = blockIdx.x * blockDim.x + threadIdx.x;
  if (e >= E) return;
  int r = row[e], c = col[e];
  const float4* hp = reinterpret_cast<const float4*>(hs + (size_t)c * 8);
  float4 a = hp[0], b = hp[1];
  float* ap = acc + (size_t)r * 8;
  atomicAdd(ap + 0, a.x); atomicAdd(ap + 1, a.y);
  atomicAdd(ap + 2, a.z); atomicAdd(ap + 3, a.w);
  atomicAdd(ap + 4, b.x); atomicAdd(ap + 5, b.y);
  atomicAdd(ap + 6, b.z); atomicAdd(ap + 7, b.w);
}

__global__ void __launch_bounds__(256)
k_finalize(const float* __restrict__ hs, const float* __restrict__ acc,
           const unsigned* __restrict__ deg,
           const float* __restrict__ w1, const float* __restrict__ b1,
           const float* __restrict__ w2, const float* __restrict__ b2,
           const float* __restrict__ w3, const float* __restrict__ b3,
           float* __restrict__ xn, int N) {
  __shared__ float sW1[8 * 32], sB1[32], sW2[32 * 16], sB2[16], sW3[16 * 16], sB3[16];
  for (int t = threadIdx.x; t < 256; t += blockDim.x) { sW1[t] = w1[t]; sW3[t] = w3[t]; }
  for (int t = threadIdx.x; t < 512; t += blockDim.x) sW2[t] = w2[t];
  for (int t = threadIdx.x; t < 32; t += blockDim.x) sB1[t] = b1[t];
  for (int t = threadIdx.x; t < 16; t += blockDim.x) { sB2[t] = b2[t]; sB3[t] = b3[t]; }
  __syncthreads();
  int i = blockIdx.x * blockDim.x + threadIdx.x;
  if (i >= N) return;
  float dinv = rsqrtf((float)(deg[i] + 1u));
  float a[8];
  const float4* accp = reinterpret_cast<const float4*>(acc + (size_t)i * 8);
  const float4* hsp = reinterpret_cast<const float4*>(hs + (size_t)i * 8);
  float4 a0 = accp[0], a1 = accp[1], s0 = hsp[0], s1 = hsp[1];
  a[0] = dinv * (a0.x + s0.x); a[1] = dinv * (a0.y + s0.y);
  a[2] = dinv * (a0.z + s0.z); a[3] = dinv * (a0.w + s0.w);
  a[4] = dinv * (a1.x + s1.x); a[5] = dinv * (a1.y + s1.y);
  a[6] = dinv * (a1.z + s1.z); a[7] = dinv * (a1.w + s1.w);
  float h1[32];
  #pragma unroll
  for (int o = 0; o < 32; o++) {
    float s = sB1[o];
    #pragma unroll
    for (int k = 0; k < 8; k++) s = fmaf(a[k], sW1[k * 32 + o], s);
    h1[o] = fmaxf(s, 0.f);
  }
  float h2[16];
  #pragma unroll
  for (int o = 0; o < 16; o++) {
    float s = sB2[o];
    #pragma unroll
    for (int k = 0; k < 32; k++) s = fmaf(h1[k], sW2[k * 16 + o], s);
    h2[o] = fmaxf(s, 0.f);
  }
  float o0[16];
  #pragma unroll
  for (int o = 0; o < 16; o++) {
    float s = sB3[o];
    #pragma unroll
    for (int k = 0; k < 16; k++) s = fmaf(h2[k], sW3[k * 16 + o], s);
    o0[o] = s;
  }
  float4* op = reinterpret_cast<float4*>(xn + (size_t)i * 16);
  #pragma unroll
  for (int q = 0; q < 4; q++)
    op[q] = make_float4(o0[q * 4], o0[q * 4 + 1], o0[q * 4 + 2], o0[q * 4 + 3]);
}

// ---------------------------------------------------------------------------

extern "C" void kernel_launch(void* const* d_in, const int* in_sizes, int n_in,
                              void* d_out, int out_size, void* d_ws, size_t ws_size,
                              hipStream_t stream) {
  const float* x = (const float*)d_in[0];
  const int* ei = (const int*)d_in[1];
  const int* batch = (const int*)d_in[2];
  const float* m1w1 = (const float*)d_in[4];  const float* m1b1 = (const float*)d_in[5];
  const float* m1w2 = (const float*)d_in[6];  const float* m1b2 = (const float*)d_in[7];
  const float* m1w3 = (const float*)d_in[8];  const float* m1b3 = (const float*)d_in[9];
  const float* m2w1 = (const float*)d_in[10]; const float* m2b1 = (const float*)d_in[11];
  const float* m2w2 = (const float*)d_in[12]; const float* m2b2 = (const float*)d_in[13];
  const float* m2w3 = (const float*)d_in[14]; const float* m2b3 = (const float*)d_in[15];
  const float* mdw1 = (const float*)d_in[16]; const float* mdb1 = (const float*)d_in[17];
  const float* mdw2 = (const float*)d_in[18]; const float* mdb2 = (const float*)d_in[19];
  const float* mdw3 = (const float*)d_in[20]; const float* mdb3 = (const float*)d_in[21];
  const float* mgw1 = (const float*)d_in[22]; const float* mgb1 = (const float*)d_in[23];
  const float* mgw2 = (const float*)d_in[24]; const float* mgb2 = (const float*)d_in[25];
  const float* mgw3 = (const float*)d_in[26]; const float* mgb3 = (const float*)d_in[27];

  int N = in_sizes[0] / 16;
  int E = in_sizes[1] / 2;
  int G = (out_size - N * 16 - 16) / 16;
  const int* rowp = ei;       // aggregation (destination) index
  const int* colp = ei + E;   // message source index

  float* xn = (float*)d_out;
  float* yv = xn + (size_t)N * 16;
  float* zv = yv + (size_t)G * 16;

  int nb = (N + BSZ - 1) / BSZ;

  size_t off = 0;
  auto alloc = [&](size_t bytes) -> size_t {
    off = (off + 255) & ~(size_t)255;
    size_t o = off; off += bytes; return o;
  };
  char* ws = (char*)d_ws;
  size_t o_deg  = alloc((size_t)N * 4);
  size_t o_hs16 = alloc((size_t)N * 16);
  size_t o_bkt  = alloc((size_t)6 * NBMAX * 4);
  size_t o_eb   = alloc(((size_t)E + 4 * NBMAX) * 4);   // padded row buckets
  size_t o_eb2  = alloc((size_t)E * 2);
  size_t o_pool = alloc((size_t)G * 32 * 4);
  size_t need = off;

  bool bucketed = (ws_size >= need) && (nb <= NBMAX) && (N <= (1 << 18));

  if (bucketed) {
    unsigned* deg = (unsigned*)(ws + o_deg);
    uint4* hs16 = (uint4*)(ws + o_hs16);
    unsigned* tot_r  = (unsigned*)(ws + o_bkt);
    unsigned* offs_r = tot_r + NBMAX;
    unsigned* cur_r  = tot_r + 2 * NBMAX;
    unsigned* tot_c  = tot_r + 3 * NBMAX;
    unsigned* offs_c = tot_r + 4 * NBMAX;
    unsigned* cur_c  = tot_r + 5 * NBMAX;
    unsigned* ebuf = (unsigned*)(ws + o_eb);
    unsigned short* ebuf2 = (unsigned short*)(ws + o_eb2);
    float* pool = (float*)(ws + o_pool);

    hipMemsetAsync(ws + o_bkt, 0, (size_t)6 * NBMAX * 4, stream);

    // fused count of row+col keys (one edge_index pass), fused scan
    k_count2<<<512, 256, 0, stream>>>(rowp, colp, E, nb, tot_r, tot_c);
    k_scan2<<<2, 1024, 0, stream>>>(tot_r, offs_r, cur_r, tot_c, offs_c, cur_c, nb);

    // degree path: bucket col -> per-bucket histogram
    k_scat_col<<<256, 256, 0, stream>>>(colp, E, nb, cur_c, ebuf2);
    k_degb<<<nb, 256, 0, stream>>>(ebuf2, offs_c, tot_c, deg, N);

    // aggregation path: bucket edges by row (buckets padded to x4)
    k_scat_row<<<256, 256, 0, stream>>>(rowp, colp, E, nb, cur_r, ebuf);

    k_mlp1<<<(N + 255) / 256, 256, 0, stream>>>(x, deg, m1w1, m1b1, m1w2, m1b2, m1w3, m1b3, hs16, N);
    k_agg<<<nb, 256, 0, stream>>>(ebuf, offs_r, tot_r, hs16, deg,
                                  m2w1, m2b1, m2w2, m2b2, m2w3, m2b3, xn, N);

    k_pool<<<G, 256, 0, stream>>>(x, xn, batch, pool, N);
    k_dag<<<(G + 255) / 256, 256, 0, stream>>>(pool, mdw1, mdb1, mdw2, mdb2, mdw3, mdb3, yv, G);
    k_z<<<1, 256, 0, stream>>>(yv, mgw1, mgb1, mgw2, mgb2, mgw3, mgb3, zv, G);
  } else {
    unsigned* deg = (unsigned*)ws;
    float* acc = (float*)(ws + (size_t)N * 4);
    float* hs  = (float*)(ws + (size_t)N * 36);
    float* pool = (float*)(ws + (size_t)N * 68);

    hipMemsetAsync(ws, 0, (size_t)N * 36, stream);
    const int TB = 256;
    k_deg_atomic<<<(E + TB - 1) / TB, TB, 0, stream>>>(colp, deg, E);
    k_mlp1f<<<(N + TB - 1) / TB, TB, 0, stream>>>(x, deg, m1w1, m1b1, m1w2, m1b2, m1w3, m1b3, hs, N);
    k_scatter_atomic<<<(E + TB - 1) / TB, TB, 0, stream>>>(rowp, colp, hs, acc, E);
    k_finalize<<<(N + TB - 1) / TB, TB, 0, stream>>>(hs, acc, deg, m2w1, m2b1, m2w2, m2b2, m2w3, m2b3, xn, N);
    k_pool<<<G, TB, 0, stream>>>(x, xn, batch, pool, N);
    k_dag<<<(G + TB - 1) / TB, TB, 0, stream>>>(pool, mdw1, mdb1, mdw2, mdb2, mdw3, mdb3, yv, G);
    k_z<<<1, TB, 0, stream>>>(yv, mgw1, mgb1, mgw2, mgb2, mgw3, mgb3, zv, G);
  }
}

// Round 5
// 389.811 us; speedup vs baseline: 7.3761x; 1.6011x over previous
//
#include <hip/hip_runtime.h>
#include <hip/hip_fp16.h>

// ---------------------------------------------------------------------------
// GraphEncoderNetwork: GCNConv(mlp1 -> norm scatter -> mlp2) + pooled mlp_dag
// + global mlp. All fp32. N=200000, E=6400000, G=1000, IN=16, D=16.
//
// Round 5: k_agg's wall was 51.2M LDS atomic lane-ops (8 ds_add_f32/edge,
// ~2-4cy/lane serialized) -- NOT gather latency. New k_agg: in-block counting
// sort by rel (2 LDS atomics/edge) then per-node register accumulation
// (0 atomics, pipelined gathers). Fused row+col scatter into one kernel.
// ---------------------------------------------------------------------------

#define BSH 7               // bucket shift
#define BSZ 128             // nodes per bucket
#define NBMAX 2048          // max buckets
#define CHUNK 4096          // edges per k_agg sort chunk (= 16 * 256)

__device__ __forceinline__ int lowerb(const int* __restrict__ b, int n, int v) {
  int lo = 0, hi = n;
  while (lo < hi) { int m = (lo + hi) >> 1; if (b[m] < v) lo = m + 1; else hi = m; }
  return lo;
}

__device__ __forceinline__ void addmsg(float* acc, uint4 g) {
  const __half2* h2 = reinterpret_cast<const __half2*>(&g);
  #pragma unroll
  for (int q = 0; q < 4; q++) {
    float2 f = __half22float2(h2[q]);
    acc[2 * q] += f.x;
    acc[2 * q + 1] += f.y;
  }
}

// ---------------- bucketing machinery --------------------------------------

// fused: count row-keys and col-keys per bucket in one pass over edge_index
__global__ void __launch_bounds__(256)
k_count2(const int* __restrict__ row, const int* __restrict__ col, int E, int nb,
         unsigned* __restrict__ tot_r, unsigned* __restrict__ tot_c) {
  __shared__ unsigned hr[NBMAX];
  __shared__ unsigned hc[NBMAX];
  int t = threadIdx.x;
  for (int i = t; i < nb; i += 256) { hr[i] = 0; hc[i] = 0; }
  __syncthreads();
  for (int i = blockIdx.x * blockDim.x + t; i < E; i += gridDim.x * blockDim.x) {
    atomicAdd(&hr[((unsigned)row[i]) >> BSH], 1u);
    atomicAdd(&hc[((unsigned)col[i]) >> BSH], 1u);
  }
  __syncthreads();
  for (int i = t; i < nb; i += 256) {
    if (hr[i]) atomicAdd(&tot_r[i], hr[i]);
    if (hc[i]) atomicAdd(&tot_c[i], hc[i]);
  }
}

// fused scan: block 0 scans row arrays (pad x4), block 1 scans col arrays
__global__ void __launch_bounds__(1024)
k_scan2(const unsigned* __restrict__ tot_r, unsigned* __restrict__ offs_r,
        unsigned* __restrict__ cur_r,
        const unsigned* __restrict__ tot_c, unsigned* __restrict__ offs_c,
        unsigned* __restrict__ cur_c, int nb) {
  const unsigned* tot = blockIdx.x ? tot_c : tot_r;
  unsigned* offs = blockIdx.x ? offs_c : offs_r;
  unsigned* cur  = blockIdx.x ? cur_c  : cur_r;
  unsigned pm1 = blockIdx.x ? 0u : 3u;
  __shared__ unsigned s[1024];
  int t = threadIdx.x;
  unsigned e0 = (2 * t < nb) ? ((tot[2 * t] + pm1) & ~pm1) : 0u;
  unsigned e1 = (2 * t + 1 < nb) ? ((tot[2 * t + 1] + pm1) & ~pm1) : 0u;
  unsigned sum = e0 + e1;
  s[t] = sum;
  __syncthreads();
  for (int d = 1; d < 1024; d <<= 1) {
    unsigned v = (t >= d) ? s[t - d] : 0u;
    __syncthreads();
    s[t] += v;
    __syncthreads();
  }
  unsigned ex = s[t] - sum;
  if (2 * t < nb)     { offs[2 * t] = ex;          cur[2 * t] = ex; }
  if (2 * t + 1 < nb) { offs[2 * t + 1] = ex + e0; cur[2 * t + 1] = ex + e0; }
}

// fused scatter: edges into row-buckets (payload rel<<18|col) AND col keys
// into col-buckets (payload rel_col u16), one edge_index pass
__global__ void __launch_bounds__(256)
k_scat2(const int* __restrict__ row, const int* __restrict__ col, int E, int nb,
        unsigned* __restrict__ cur_r, unsigned* __restrict__ cur_c,
        unsigned* __restrict__ ebuf, unsigned short* __restrict__ ebuf2) {
  __shared__ unsigned hr[NBMAX], hc[NBMAX], br[NBMAX], bc[NBMAX];
  int t = threadIdx.x;
  int chunk = (E + gridDim.x - 1) / gridDim.x;
  int s = blockIdx.x * chunk, e = min(E, s + chunk);
  for (int i = t; i < nb; i += 256) { hr[i] = 0; hc[i] = 0; }
  __syncthreads();
  for (int i = s + t; i < e; i += 256) {
    atomicAdd(&hr[((unsigned)row[i]) >> BSH], 1u);
    atomicAdd(&hc[((unsigned)col[i]) >> BSH], 1u);
  }
  __syncthreads();
  for (int i = t; i < nb; i += 256) {
    unsigned c1 = hr[i];
    br[i] = c1 ? atomicAdd(&cur_r[i], c1) : 0u;
    hr[i] = 0;
    unsigned c2 = hc[i];
    bc[i] = c2 ? atomicAdd(&cur_c[i], c2) : 0u;
    hc[i] = 0;
  }
  __syncthreads();
  for (int i = s + t; i < e; i += 256) {
    unsigned r = (unsigned)row[i], c = (unsigned)col[i];
    unsigned b1 = r >> BSH, b2 = c >> BSH;
    unsigned p1 = br[b1] + atomicAdd(&hr[b1], 1u);
    ebuf[p1] = ((r & (BSZ - 1u)) << 18) | c;
    unsigned p2 = bc[b2] + atomicAdd(&hc[b2], 1u);
    ebuf2[p2] = (unsigned short)(c & (BSZ - 1u));
  }
}

// per-bucket degree histogram (LDS), direct write
__global__ void __launch_bounds__(256)
k_degb(const unsigned short* __restrict__ eb, const unsigned* __restrict__ offs,
       const unsigned* __restrict__ tot, unsigned* __restrict__ deg, int N) {
  __shared__ unsigned cnt[BSZ];
  int b = blockIdx.x, t = threadIdx.x;
  if (t < BSZ) cnt[t] = 0;
  __syncthreads();
  unsigned s = offs[b], n = tot[b];
  for (unsigned i = t; i < n; i += 256) atomicAdd(&cnt[eb[s + i]], 1u);
  __syncthreads();
  int node = b * BSZ + t;
  if (t < BSZ && node < N) deg[node] = cnt[t];
}

// ---------------- node MLPs ------------------------------------------------

// mlp1 per node -> h[8]; store hs16 = fp16x8 of dinv * h
__global__ void __launch_bounds__(256)
k_mlp1(const float* __restrict__ x, const unsigned* __restrict__ deg,
       const float* __restrict__ w1, const float* __restrict__ b1,
       const float* __restrict__ w2, const float* __restrict__ b2,
       const float* __restrict__ w3, const float* __restrict__ b3,
       uint4* __restrict__ hs16, int N) {
  __shared__ float sW1[16 * 32], sB1[32], sW2[32 * 16], sB2[16], sW3[16 * 8], sB3[8];
  for (int t = threadIdx.x; t < 512; t += blockDim.x) { sW1[t] = w1[t]; sW2[t] = w2[t]; }
  for (int t = threadIdx.x; t < 128; t += blockDim.x) sW3[t] = w3[t];
  for (int t = threadIdx.x; t < 32; t += blockDim.x) sB1[t] = b1[t];
  for (int t = threadIdx.x; t < 16; t += blockDim.x) sB2[t] = b2[t];
  for (int t = threadIdx.x; t < 8; t += blockDim.x) sB3[t] = b3[t];
  __syncthreads();
  int i = blockIdx.x * blockDim.x + threadIdx.x;
  if (i >= N) return;

  float xin[16];
  const float4* xp = reinterpret_cast<const float4*>(x + (size_t)i * 16);
  #pragma unroll
  for (int q = 0; q < 4; q++) {
    float4 v = xp[q];
    xin[q * 4 + 0] = v.x; xin[q * 4 + 1] = v.y; xin[q * 4 + 2] = v.z; xin[q * 4 + 3] = v.w;
  }
  float h1[32];
  #pragma unroll
  for (int o = 0; o < 32; o++) {
    float s = sB1[o];
    #pragma unroll
    for (int k = 0; k < 16; k++) s = fmaf(xin[k], sW1[k * 32 + o], s);
    h1[o] = fmaxf(s, 0.f);
  }
  float h2[16];
  #pragma unroll
  for (int o = 0; o < 16; o++) {
    float s = sB2[o];
    #pragma unroll
    for (int k = 0; k < 32; k++) s = fmaf(h1[k], sW2[k * 16 + o], s);
    h2[o] = fmaxf(s, 0.f);
  }
  float dinv = rsqrtf((float)(deg[i] + 1u));  // +1 self-loop
  float o0[8];
  #pragma unroll
  for (int o = 0; o < 8; o++) {
    float s = sB3[o];
    #pragma unroll
    for (int k = 0; k < 16; k++) s = fmaf(h2[k], sW3[k * 8 + o], s);
    o0[o] = dinv * s;
  }
  __half2 hh[4];
  #pragma unroll
  for (int q = 0; q < 4; q++) hh[q] = __floats2half2_rn(o0[2 * q], o0[2 * q + 1]);
  hs16[i] = *reinterpret_cast<const uint4*>(hh);
}

// per-bucket: in-block counting sort by rel, register accumulation (no
// per-edge LDS atomics), then self-loop + mlp2 inline
__global__ void __launch_bounds__(256)
k_agg(const unsigned* __restrict__ ebuf, const unsigned* __restrict__ offs,
      const unsigned* __restrict__ tot,
      const uint4* __restrict__ hs16, const unsigned* __restrict__ deg,
      const float* __restrict__ w1, const float* __restrict__ b1,
      const float* __restrict__ w2, const float* __restrict__ b2,
      const float* __restrict__ w3, const float* __restrict__ b3,
      float* __restrict__ xn, int N) {
  __shared__ unsigned sorted[CHUNK];       // 16 KB: col ids sorted by rel
  __shared__ unsigned hist[132];
  __shared__ unsigned cum[132];
  __shared__ unsigned cur[132];
  __shared__ unsigned scan_tmp[256];
  __shared__ float stage[BSZ][9];          // pad 9: avoid bank conflicts
  __shared__ float sW1[8 * 32], sB1[32], sW2[32 * 16], sB2[16], sW3[16 * 16], sB3[16];
  int t = threadIdx.x;
  sW1[t] = w1[t]; sW3[t] = w3[t];          // 256 each
  for (int i = t; i < 512; i += 256) sW2[i] = w2[i];
  if (t < 32) sB1[t] = b1[t];
  if (t < 16) { sB2[t] = b2[t]; sB3[t] = b3[t]; }

  int b = blockIdx.x;
  unsigned s = offs[b], n = tot[b];
  unsigned nr = (n + 3u) & ~3u;            // padded region is allocated

  float acc[8];
  #pragma unroll
  for (int c = 0; c < 8; c++) acc[c] = 0.f;
  int nl = t >> 1, half = t & 1;

  for (unsigned c0 = 0; c0 < n; c0 += CHUNK) {
    if (t < 132) hist[t] = 0;
    __syncthreads();

    // load up to 16 edges (coalesced uint4), classify
    unsigned rel[16], colv[16];
    #pragma unroll
    for (int u = 0; u < 4; u++) {
      unsigned idx = c0 + 4 * (unsigned)(t + 256 * u);
      uint4 pk = make_uint4(0u, 0u, 0u, 0u);
      if (idx < nr) pk = *reinterpret_cast<const uint4*>(ebuf + s + idx);
      #pragma unroll
      for (int j = 0; j < 4; j++) {
        bool real = (idx + j) < n;
        unsigned p = (&pk.x)[j];
        rel[4 * u + j]  = real ? (p >> 18) : 128u;     // 128 = sentinel bin
        colv[4 * u + j] = real ? (p & 0x3FFFFu) : 0u;
      }
    }
    // histogram (1 LDS atomic/edge)
    #pragma unroll
    for (int u = 0; u < 16; u++) atomicAdd(&hist[rel[u]], 1u);
    __syncthreads();
    // exclusive scan over 129 bins (Hillis-Steele, 256 threads)
    unsigned hv = (t < 129) ? hist[t] : 0u;
    scan_tmp[t] = hv;
    __syncthreads();
    for (int d = 1; d < 256; d <<= 1) {
      unsigned v = (t >= d) ? scan_tmp[t - d] : 0u;
      __syncthreads();
      scan_tmp[t] += v;
      __syncthreads();
    }
    if (t < 129) { cum[t] = scan_tmp[t] - hv; cur[t] = scan_tmp[t] - hv; }
    __syncthreads();
    // scatter into sorted order (1 LDS atomic/edge)
    #pragma unroll
    for (int u = 0; u < 16; u++) {
      unsigned pos = atomicAdd(&cur[rel[u]], 1u);
      sorted[pos] = colv[u];
    }
    __syncthreads();
    // register accumulation: 2 threads per node, contiguous halves
    unsigned lo = cum[nl], hi = cum[nl + 1];
    unsigned len = hi - lo, mid = lo + (len >> 1);
    unsigned a0 = half ? mid : lo;
    unsigned a1 = half ? hi : mid;
    unsigned i = a0;
    for (; i + 4 <= a1; i += 4) {
      unsigned q0 = sorted[i], q1 = sorted[i + 1], q2 = sorted[i + 2], q3 = sorted[i + 3];
      uint4 g0 = hs16[q0];
      uint4 g1 = hs16[q1];
      uint4 g2 = hs16[q2];
      uint4 g3 = hs16[q3];
      addmsg(acc, g0); addmsg(acc, g1); addmsg(acc, g2); addmsg(acc, g3);
    }
    for (; i < a1; i++) { uint4 g = hs16[sorted[i]]; addmsg(acc, g); }
    __syncthreads();   // protect sorted/hist reuse next chunk
  }

  // combine halves (no atomics: ordered by barriers)
  if (!half) {
    #pragma unroll
    for (int c = 0; c < 8; c++) stage[nl][c] = acc[c];
  }
  __syncthreads();
  if (half) {
    #pragma unroll
    for (int c = 0; c < 8; c++) stage[nl][c] += acc[c];
  }
  __syncthreads();

  int node = b * BSZ + t;
  if (t >= BSZ || node >= N) return;
  float dinv = rsqrtf((float)(deg[node] + 1u));
  uint4 selfp = hs16[node];
  const __half2* sh = reinterpret_cast<const __half2*>(&selfp);
  float a[8];
  #pragma unroll
  for (int q = 0; q < 4; q++) {
    float2 f = __half22float2(sh[q]);
    a[2 * q]     = dinv * (stage[t][2 * q] + f.x);
    a[2 * q + 1] = dinv * (stage[t][2 * q + 1] + f.y);
  }

  float h1[32];
  #pragma unroll
  for (int o = 0; o < 32; o++) {
    float v = sB1[o];
    #pragma unroll
    for (int k = 0; k < 8; k++) v = fmaf(a[k], sW1[k * 32 + o], v);
    h1[o] = fmaxf(v, 0.f);
  }
  float h2v[16];
  #pragma unroll
  for (int o = 0; o < 16; o++) {
    float v = sB2[o];
    #pragma unroll
    for (int k = 0; k < 32; k++) v = fmaf(h1[k], sW2[k * 16 + o], v);
    h2v[o] = fmaxf(v, 0.f);
  }
  float o0[16];
  #pragma unroll
  for (int o = 0; o < 16; o++) {
    float v = sB3[o];
    #pragma unroll
    for (int k = 0; k < 16; k++) v = fmaf(h2v[k], sW3[k * 16 + o], v);
    o0[o] = v;
  }
  float4* op = reinterpret_cast<float4*>(xn + (size_t)node * 16);
  #pragma unroll
  for (int q = 0; q < 4; q++)
    op[q] = make_float4(o0[q * 4], o0[q * 4 + 1], o0[q * 4 + 2], o0[q * 4 + 3]);
}

// ---------------- pooling + graph/global MLPs ------------------------------

__global__ void __launch_bounds__(256)
k_pool(const float* __restrict__ x, const float* __restrict__ xn,
       const int* __restrict__ batch, float* __restrict__ pool, int N) {
  int g = blockIdx.x;
  int lo = lowerb(batch, N, g);
  int hi = lowerb(batch, N, g + 1);
  int c = threadIdx.x & 31;
  int j = threadIdx.x >> 5;
  float s = 0.f;
  for (int n = lo + j; n < hi; n += 8) {
    s += (c < 16) ? x[(size_t)n * 16 + c] : xn[(size_t)n * 16 + (c - 16)];
  }
  __shared__ float red[8][33];
  red[j][c] = s;
  __syncthreads();
  if (threadIdx.x < 32) {
    float t = 0.f;
    #pragma unroll
    for (int q = 0; q < 8; q++) t += red[q][threadIdx.x];
    pool[(size_t)g * 32 + threadIdx.x] = t;
  }
}

__global__ void __launch_bounds__(256)
k_dag(const float* __restrict__ pool,
      const float* __restrict__ w1, const float* __restrict__ b1,
      const float* __restrict__ w2, const float* __restrict__ b2,
      const float* __restrict__ w3, const float* __restrict__ b3,
      float* __restrict__ y, int G) {
  __shared__ float sW1[32 * 32], sB1[32], sW2[32 * 16], sB2[16], sW3[16 * 16], sB3[16];
  for (int t = threadIdx.x; t < 1024; t += blockDim.x) sW1[t] = w1[t];
  for (int t = threadIdx.x; t < 512; t += blockDim.x) sW2[t] = w2[t];
  for (int t = threadIdx.x; t < 256; t += blockDim.x) sW3[t] = w3[t];
  for (int t = threadIdx.x; t < 32; t += blockDim.x) sB1[t] = b1[t];
  for (int t = threadIdx.x; t < 16; t += blockDim.x) { sB2[t] = b2[t]; sB3[t] = b3[t]; }
  __syncthreads();
  int g = blockIdx.x * blockDim.x + threadIdx.x;
  if (g >= G) return;

  float in[32];
  const float4* pp = reinterpret_cast<const float4*>(pool + (size_t)g * 32);
  #pragma unroll
  for (int q = 0; q < 8; q++) {
    float4 v = pp[q];
    in[q * 4 + 0] = v.x; in[q * 4 + 1] = v.y; in[q * 4 + 2] = v.z; in[q * 4 + 3] = v.w;
  }
  float h1[32];
  #pragma unroll
  for (int o = 0; o < 32; o++) {
    float s = sB1[o];
    #pragma unroll
    for (int k = 0; k < 32; k++) s = fmaf(in[k], sW1[k * 32 + o], s);
    h1[o] = fmaxf(s, 0.f);
  }
  float h2[16];
  #pragma unroll
  for (int o = 0; o < 16; o++) {
    float s = sB2[o];
    #pragma unroll
    for (int k = 0; k < 32; k++) s = fmaf(h1[k], sW2[k * 16 + o], s);
    h2[o] = fmaxf(s, 0.f);
  }
  float o0[16];
  #pragma unroll
  for (int o = 0; o < 16; o++) {
    float s = sB3[o];
    #pragma unroll
    for (int k = 0; k < 16; k++) s = fmaf(h2[k], sW3[k * 16 + o], s);
    o0[o] = s;
  }
  float4* yp = reinterpret_cast<float4*>(y + (size_t)g * 16);
  #pragma unroll
  for (int q = 0; q < 4; q++)
    yp[q] = make_float4(o0[q * 4], o0[q * 4 + 1], o0[q * 4 + 2], o0[q * 4 + 3]);
}

__global__ void __launch_bounds__(256)
k_z(const float* __restrict__ y,
    const float* __restrict__ w1, const float* __restrict__ b1,
    const float* __restrict__ w2, const float* __restrict__ b2,
    const float* __restrict__ w3, const float* __restrict__ b3,
    float* __restrict__ z, int G) {
  __shared__ float red[16][17];
  __shared__ float sum[16], h1s[32], h2s[16];
  int t = threadIdx.x;
  int c = t & 15, j = t >> 4;
  float s = 0.f;
  for (int g = j; g < G; g += 16) s += y[(size_t)g * 16 + c];
  red[j][c] = s;
  __syncthreads();
  if (t < 16) {
    float v = 0.f;
    #pragma unroll
    for (int q = 0; q < 16; q++) v += red[q][t];
    sum[t] = v;
  }
  __syncthreads();
  if (t < 32) {
    float s1 = b1[t];
    #pragma unroll
    for (int k = 0; k < 16; k++) s1 = fmaf(sum[k], w1[k * 32 + t], s1);
    h1s[t] = fmaxf(s1, 0.f);
  }
  __syncthreads();
  if (t < 16) {
    float s2 = b2[t];
    #pragma unroll
    for (int k = 0; k < 32; k++) s2 = fmaf(h1s[k], w2[k * 16 + t], s2);
    h2s[t] = fmaxf(s2, 0.f);
  }
  __syncthreads();
  if (t < 16) {
    float s3 = b3[t];
    #pragma unroll
    for (int k = 0; k < 16; k++) s3 = fmaf(h2s[k], w3[k * 16 + t], s3);
    z[t] = s3;
  }
}

// ---------------- fallback (known-good atomic path) ------------------------

__global__ void k_deg_atomic(const int* __restrict__ col, unsigned* __restrict__ deg, int E) {
  int e = blockIdx.x * blockDim.x + threadIdx.x;
  if (e < E) atomicAdd(&deg[col[e]], 1u);
}

__global__ void __launch_bounds__(256)
k_mlp1f(const float* __restrict__ x, const unsigned* __restrict__ deg,
        const float* __restrict__ w1, const float* __restrict__ b1,
        const float* __restrict__ w2, const float* __restrict__ b2,
        const float* __restrict__ w3, const float* __restrict__ b3,
        float* __restrict__ hs, int N) {
  __shared__ float sW1[16 * 32], sB1[32], sW2[32 * 16], sB2[16], sW3[16 * 8], sB3[8];
  for (int t = threadIdx.x; t < 512; t += blockDim.x) { sW1[t] = w1[t]; sW2[t] = w2[t]; }
  for (int t = threadIdx.x; t < 128; t += blockDim.x) sW3[t] = w3[t];
  for (int t = threadIdx.x; t < 32; t += blockDim.x) sB1[t] = b1[t];
  for (int t = threadIdx.x; t < 16; t += blockDim.x) sB2[t] = b2[t];
  for (int t = threadIdx.x; t < 8; t += blockDim.x) sB3[t] = b3[t];
  __syncthreads();
  int i = blockIdx.x * blockDim.x + threadIdx.x;
  if (i >= N) return;
  float xin[16];
  const float4* xp = reinterpret_cast<const float4*>(x + (size_t)i * 16);
  #pragma unroll
  for (int q = 0; q < 4; q++) {
    float4 v = xp[q];
    xin[q * 4 + 0] = v.x; xin[q * 4 + 1] = v.y; xin[q * 4 + 2] = v.z; xin[q * 4 + 3] = v.w;
  }
  float h1[32];
  #pragma unroll
  for (int o = 0; o < 32; o++) {
    float s = sB1[o];
    #pragma unroll
    for (int k = 0; k < 16; k++) s = fmaf(xin[k], sW1[k * 32 + o], s);
    h1[o] = fmaxf(s, 0.f);
  }
  float h2[16];
  #pragma unroll
  for (int o = 0; o < 16; o++) {
    float s = sB2[o];
    #pragma unroll
    for (int k = 0; k < 32; k++) s = fmaf(h1[k], sW2[k * 16 + o], s);
    h2[o] = fmaxf(s, 0.f);
  }
  float dinv = rsqrtf((float)(deg[i] + 1u));
  float o0[8];
  #pragma unroll
  for (int o = 0; o < 8; o++) {
    float s = sB3[o];
    #pragma unroll
    for (int k = 0; k < 16; k++) s = fmaf(h2[k], sW3[k * 8 + o], s);
    o0[o] = dinv * s;
  }
  float4* hp = reinterpret_cast<float4*>(hs + (size_t)i * 8);
  hp[0] = make_float4(o0[0], o0[1], o0[2], o0[3]);
  hp[1] = make_float4(o0[4], o0[5], o0[6], o0[7]);
}

__global__ void k_scatter_atomic(const int* __restrict__ row, const int* __restrict__ col,
                                 const float* __restrict__ hs, float* __restrict__ acc, int E) {
  int e = blockIdx.x * blockDim.x + threadIdx.x;
  if (e >= E) return;
  int r = row[e], c = col[e];
  const float4* hp = reinterpret_cast<const float4*>(hs + (size_t)c * 8);
  float4 a = hp[0], b = hp[1];
  float* ap = acc + (size_t)r * 8;
  atomicAdd(ap + 0, a.x); atomicAdd(ap + 1, a.y);
  atomicAdd(ap + 2, a.z); atomicAdd(ap + 3, a.w);
  atomicAdd(ap + 4, b.x); atomicAdd(ap + 5, b.y);
  atomicAdd(ap + 6, b.z); atomicAdd(ap + 7, b.w);
}

__global__ void __launch_bounds__(256)
k_finalize(const float* __restrict__ hs, const float* __restrict__ acc,
           const unsigned* __restrict__ deg,
           const float* __restrict__ w1, const float* __restrict__ b1,
           const float* __restrict__ w2, const float* __restrict__ b2,
           const float* __restrict__ w3, const float* __restrict__ b3,
           float* __restrict__ xn, int N) {
  __shared__ float sW1[8 * 32], sB1[32], sW2[32 * 16], sB2[16], sW3[16 * 16], sB3[16];
  for (int t = threadIdx.x; t < 256; t += blockDim.x) { sW1[t] = w1[t]; sW3[t] = w3[t]; }
  for (int t = threadIdx.x; t < 512; t += blockDim.x) sW2[t] = w2[t];
  for (int t = threadIdx.x; t < 32; t += blockDim.x) sB1[t] = b1[t];
  for (int t = threadIdx.x; t < 16; t += blockDim.x) { sB2[t] = b2[t]; sB3[t] = b3[t]; }
  __syncthreads();
  int i = blockIdx.x * blockDim.x + threadIdx.x;
  if (i >= N) return;
  float dinv = rsqrtf((float)(deg[i] + 1u));
  float a[8];
  const float4* accp = reinterpret_cast<const float4*>(acc + (size_t)i * 8);
  const float4* hsp = reinterpret_cast<const float4*>(hs + (size_t)i * 8);
  float4 a0 = accp[0], a1 = accp[1], s0 = hsp[0], s1 = hsp[1];
  a[0] = dinv * (a0.x + s0.x); a[1] = dinv * (a0.y + s0.y);
  a[2] = dinv * (a0.z + s0.z); a[3] = dinv * (a0.w + s0.w);
  a[4] = dinv * (a1.x + s1.x); a[5] = dinv * (a1.y + s1.y);
  a[6] = dinv * (a1.z + s1.z); a[7] = dinv * (a1.w + s1.w);
  float h1[32];
  #pragma unroll
  for (int o = 0; o < 32; o++) {
    float s = sB1[o];
    #pragma unroll
    for (int k = 0; k < 8; k++) s = fmaf(a[k], sW1[k * 32 + o], s);
    h1[o] = fmaxf(s, 0.f);
  }
  float h2[16];
  #pragma unroll
  for (int o = 0; o < 16; o++) {
    float s = sB2[o];
    #pragma unroll
    for (int k = 0; k < 32; k++) s = fmaf(h1[k], sW2[k * 16 + o], s);
    h2[o] = fmaxf(s, 0.f);
  }
  float o0[16];
  #pragma unroll
  for (int o = 0; o < 16; o++) {
    float s = sB3[o];
    #pragma unroll
    for (int k = 0; k < 16; k++) s = fmaf(h2[k], sW3[k * 16 + o], s);
    o0[o] = s;
  }
  float4* op = reinterpret_cast<float4*>(xn + (size_t)i * 16);
  #pragma unroll
  for (int q = 0; q < 4; q++)
    op[q] = make_float4(o0[q * 4], o0[q * 4 + 1], o0[q * 4 + 2], o0[q * 4 + 3]);
}

// ---------------------------------------------------------------------------

extern "C" void kernel_launch(void* const* d_in, const int* in_sizes, int n_in,
                              void* d_out, int out_size, void* d_ws, size_t ws_size,
                              hipStream_t stream) {
  const float* x = (const float*)d_in[0];
  const int* ei = (const int*)d_in[1];
  const int* batch = (const int*)d_in[2];
  const float* m1w1 = (const float*)d_in[4];  const float* m1b1 = (const float*)d_in[5];
  const float* m1w2 = (const float*)d_in[6];  const float* m1b2 = (const float*)d_in[7];
  const float* m1w3 = (const float*)d_in[8];  const float* m1b3 = (const float*)d_in[9];
  const float* m2w1 = (const float*)d_in[10]; const float* m2b1 = (const float*)d_in[11];
  const float* m2w2 = (const float*)d_in[12]; const float* m2b2 = (const float*)d_in[13];
  const float* m2w3 = (const float*)d_in[14]; const float* m2b3 = (const float*)d_in[15];
  const float* mdw1 = (const float*)d_in[16]; const float* mdb1 = (const float*)d_in[17];
  const float* mdw2 = (const float*)d_in[18]; const float* mdb2 = (const float*)d_in[19];
  const float* mdw3 = (const float*)d_in[20]; const float* mdb3 = (const float*)d_in[21];
  const float* mgw1 = (const float*)d_in[22]; const float* mgb1 = (const float*)d_in[23];
  const float* mgw2 = (const float*)d_in[24]; const float* mgb2 = (const float*)d_in[25];
  const float* mgw3 = (const float*)d_in[26]; const float* mgb3 = (const float*)d_in[27];

  int N = in_sizes[0] / 16;
  int E = in_sizes[1] / 2;
  int G = (out_size - N * 16 - 16) / 16;
  const int* rowp = ei;       // aggregation (destination) index
  const int* colp = ei + E;   // message source index

  float* xn = (float*)d_out;
  float* yv = xn + (size_t)N * 16;
  float* zv = yv + (size_t)G * 16;

  int nb = (N + BSZ - 1) / BSZ;

  size_t off = 0;
  auto alloc = [&](size_t bytes) -> size_t {
    off = (off + 255) & ~(size_t)255;
    size_t o = off; off += bytes; return o;
  };
  char* ws = (char*)d_ws;
  size_t o_deg  = alloc((size_t)N * 4);
  size_t o_hs16 = alloc((size_t)N * 16);
  size_t o_bkt  = alloc((size_t)6 * NBMAX * 4);
  size_t o_eb   = alloc(((size_t)E + 4 * NBMAX) * 4);   // padded row buckets
  size_t o_eb2  = alloc((size_t)E * 2);
  size_t o_pool = alloc((size_t)G * 32 * 4);
  size_t need = off;

  bool bucketed = (ws_size >= need) && (nb <= NBMAX) && (N <= (1 << 18));

  if (bucketed) {
    unsigned* deg = (unsigned*)(ws + o_deg);
    uint4* hs16 = (uint4*)(ws + o_hs16);
    unsigned* tot_r  = (unsigned*)(ws + o_bkt);
    unsigned* offs_r = tot_r + NBMAX;
    unsigned* cur_r  = tot_r + 2 * NBMAX;
    unsigned* tot_c  = tot_r + 3 * NBMAX;
    unsigned* offs_c = tot_r + 4 * NBMAX;
    unsigned* cur_c  = tot_r + 5 * NBMAX;
    unsigned* ebuf = (unsigned*)(ws + o_eb);
    unsigned short* ebuf2 = (unsigned short*)(ws + o_eb2);
    float* pool = (float*)(ws + o_pool);

    hipMemsetAsync(ws + o_bkt, 0, (size_t)6 * NBMAX * 4, stream);

    k_count2<<<512, 256, 0, stream>>>(rowp, colp, E, nb, tot_r, tot_c);
    k_scan2<<<2, 1024, 0, stream>>>(tot_r, offs_r, cur_r, tot_c, offs_c, cur_c, nb);
    k_scat2<<<256, 256, 0, stream>>>(rowp, colp, E, nb, cur_r, cur_c, ebuf, ebuf2);
    k_degb<<<nb, 256, 0, stream>>>(ebuf2, offs_c, tot_c, deg, N);

    k_mlp1<<<(N + 255) / 256, 256, 0, stream>>>(x, deg, m1w1, m1b1, m1w2, m1b2, m1w3, m1b3, hs16, N);
    k_agg<<<nb, 256, 0, stream>>>(ebuf, offs_r, tot_r, hs16, deg,
                                  m2w1, m2b1, m2w2, m2b2, m2w3, m2b3, xn, N);

    k_pool<<<G, 256, 0, stream>>>(x, xn, batch, pool, N);
    k_dag<<<(G + 255) / 256, 256, 0, stream>>>(pool, mdw1, mdb1, mdw2, mdb2, mdw3, mdb3, yv, G);
    k_z<<<1, 256, 0, stream>>>(yv, mgw1, mgb1, mgw2, mgb2, mgw3, mgb3, zv, G);
  } else {
    unsigned* deg = (unsigned*)ws;
    float* acc = (float*)(ws + (size_t)N * 4);
    float* hs  = (float*)(ws + (size_t)N * 36);
    float* pool = (float*)(ws + (size_t)N * 68);

    hipMemsetAsync(ws, 0, (size_t)N * 36, stream);
    const int TB = 256;
    k_deg_atomic<<<(E + TB - 1) / TB, TB, 0, stream>>>(colp, deg, E);
    k_mlp1f<<<(N + TB - 1) / TB, TB, 0, stream>>>(x, deg, m1w1, m1b1, m1w2, m1b2, m1w3, m1b3, hs, N);
    k_scatter_atomic<<<(E + TB - 1) / TB, TB, 0, stream>>>(rowp, colp, hs, acc, E);
    k_finalize<<<(N + TB - 1) / TB, TB, 0, stream>>>(hs, acc, deg, m2w1, m2b1, m2w2, m2b2, m2w3, m2b3, xn, N);
    k_pool<<<G, TB, 0, stream>>>(x, xn, batch, pool, N);
    k_dag<<<(G + TB - 1) / TB, TB, 0, stream>>>(pool, mdw1, mdb1, mdw2, mdb2, mdw3, mdb3, yv, G);
    k_z<<<1, TB, 0, stream>>>(yv, mgw1, mgb1, mgw2, mgb2, mgw3, mgb3, zv, G);
  }
}

// Round 6
// 389.591 us; speedup vs baseline: 7.3803x; 1.0006x over previous
//
#include <hip/hip_runtime.h>
#include <hip/hip_fp16.h>

// ---------------------------------------------------------------------------
// GraphEncoderNetwork: GCNConv(mlp1 -> norm scatter -> mlp2) + pooled mlp_dag
// + global mlp. All fp32. N=200000, E=6400000, G=1000, IN=16, D=16.
//
// Round 6: k_scat2 had ~10x write amplification (random per-lane 4B/2B
// scatters) + 1 block/CU. New k_scat2: per-4096-edge-tile LDS reorder
// (hist -> scan -> per-bucket base reservation -> rank -> coalesced run
// writes), grid 1563. BSZ 128->256 (longer runs); k_agg now 1 thread/node
// with register accumulator feeding mlp2 directly.
// ---------------------------------------------------------------------------

#define BSH 8               // bucket shift
#define BSZ 256             // nodes per bucket
#define NBMAX 1024          // max buckets (N <= 2^18)
#define TSZ 4096            // edges per tile / sort chunk

__device__ __forceinline__ int lowerb(const int* __restrict__ b, int n, int v) {
  int lo = 0, hi = n;
  while (lo < hi) { int m = (lo + hi) >> 1; if (b[m] < v) lo = m + 1; else hi = m; }
  return lo;
}

__device__ __forceinline__ void addmsg(float* acc, uint4 g) {
  const __half2* h2 = reinterpret_cast<const __half2*>(&g);
  #pragma unroll
  for (int q = 0; q < 4; q++) {
    float2 f = __half22float2(h2[q]);
    acc[2 * q] += f.x;
    acc[2 * q + 1] += f.y;
  }
}

// ---------------- bucketing machinery --------------------------------------

// fused: count row-keys and col-keys per bucket in one pass (uint4 loads)
__global__ void __launch_bounds__(256)
k_count2(const int* __restrict__ row, const int* __restrict__ col, int E, int nb,
         unsigned* __restrict__ tot_r, unsigned* __restrict__ tot_c) {
  __shared__ unsigned hr[NBMAX];
  __shared__ unsigned hc[NBMAX];
  int t = threadIdx.x;
  for (int i = t; i < NBMAX; i += 256) { hr[i] = 0; hc[i] = 0; }
  __syncthreads();
  int E4 = E & ~3;
  int stride = gridDim.x * 256 * 4;
  for (int i = (blockIdx.x * 256 + t) * 4; i < E4; i += stride) {
    uint4 r4 = *reinterpret_cast<const uint4*>(row + i);
    uint4 c4 = *reinterpret_cast<const uint4*>(col + i);
    atomicAdd(&hr[r4.x >> BSH], 1u); atomicAdd(&hr[r4.y >> BSH], 1u);
    atomicAdd(&hr[r4.z >> BSH], 1u); atomicAdd(&hr[r4.w >> BSH], 1u);
    atomicAdd(&hc[c4.x >> BSH], 1u); atomicAdd(&hc[c4.y >> BSH], 1u);
    atomicAdd(&hc[c4.z >> BSH], 1u); atomicAdd(&hc[c4.w >> BSH], 1u);
  }
  if (blockIdx.x == 0) {
    for (int i = E4 + t; i < E; i += 256) {
      atomicAdd(&hr[((unsigned)row[i]) >> BSH], 1u);
      atomicAdd(&hc[((unsigned)col[i]) >> BSH], 1u);
    }
  }
  __syncthreads();
  for (int i = t; i < nb; i += 256) {
    if (hr[i]) atomicAdd(&tot_r[i], hr[i]);
    if (hc[i]) atomicAdd(&tot_c[i], hc[i]);
  }
}

// fused scan: block 0 scans row arrays (pad x4), block 1 scans col arrays
__global__ void __launch_bounds__(1024)
k_scan2(const unsigned* __restrict__ tot_r, unsigned* __restrict__ offs_r,
        unsigned* __restrict__ cur_r,
        const unsigned* __restrict__ tot_c, unsigned* __restrict__ offs_c,
        unsigned* __restrict__ cur_c, int nb) {
  const unsigned* tot = blockIdx.x ? tot_c : tot_r;
  unsigned* offs = blockIdx.x ? offs_c : offs_r;
  unsigned* cur  = blockIdx.x ? cur_c  : cur_r;
  unsigned pm1 = blockIdx.x ? 0u : 3u;
  __shared__ unsigned s[1024];
  int t = threadIdx.x;
  unsigned e0 = (2 * t < nb) ? ((tot[2 * t] + pm1) & ~pm1) : 0u;
  unsigned e1 = (2 * t + 1 < nb) ? ((tot[2 * t + 1] + pm1) & ~pm1) : 0u;
  unsigned sum = e0 + e1;
  s[t] = sum;
  __syncthreads();
  for (int d = 1; d < 1024; d <<= 1) {
    unsigned v = (t >= d) ? s[t - d] : 0u;
    __syncthreads();
    s[t] += v;
    __syncthreads();
  }
  unsigned ex = s[t] - sum;
  if (2 * t < nb)     { offs[2 * t] = ex;          cur[2 * t] = ex; }
  if (2 * t + 1 < nb) { offs[2 * t + 1] = ex + e0; cur[2 * t + 1] = ex + e0; }
}

// tile-local LDS reorder scatter: coalesced run writes for ebuf AND ebuf2
__global__ void __launch_bounds__(256)
k_scat2(const int* __restrict__ row, const int* __restrict__ col, int E, int nb,
        unsigned* __restrict__ cur_r, unsigned* __restrict__ cur_c,
        unsigned* __restrict__ ebuf, unsigned short* __restrict__ ebuf2) {
  __shared__ unsigned buf[TSZ];            // 16KB reordered payloads
  __shared__ unsigned short bkt[TSZ];      // 8KB bucket id per slot
  __shared__ unsigned h[NBMAX], ls[NBMAX], gb[NBMAX], cu[NBMAX];  // 16KB
  __shared__ unsigned sc[256];
  int t = threadIdx.x;
  int base = blockIdx.x * TSZ;
  int cnt = min(TSZ, E - base);

  // load 16 edges/thread (coalesced uint4; elementwise at the tail)
  unsigned rv[16], cv[16];
  #pragma unroll
  for (int u = 0; u < 4; u++) {
    int idx = base + 4 * (t + 256 * u);
    if (idx + 3 < E) {
      uint4 r4 = *reinterpret_cast<const uint4*>(row + idx);
      uint4 c4 = *reinterpret_cast<const uint4*>(col + idx);
      rv[4*u] = r4.x; rv[4*u+1] = r4.y; rv[4*u+2] = r4.z; rv[4*u+3] = r4.w;
      cv[4*u] = c4.x; cv[4*u+1] = c4.y; cv[4*u+2] = c4.z; cv[4*u+3] = c4.w;
    } else {
      #pragma unroll
      for (int j = 0; j < 4; j++) {
        bool v = (idx + j) < E;
        rv[4*u+j] = v ? (unsigned)row[idx + j] : 0u;
        cv[4*u+j] = v ? (unsigned)col[idx + j] : 0u;
      }
    }
  }

  // ================= ROW PASS =================
  for (int i = t; i < NBMAX; i += 256) h[i] = 0;
  __syncthreads();
  #pragma unroll
  for (int u = 0; u < 4; u++) {
    int l0 = 4 * (t + 256 * u);
    #pragma unroll
    for (int j = 0; j < 4; j++)
      if (l0 + j < cnt) atomicAdd(&h[rv[4*u+j] >> BSH], 1u);
  }
  __syncthreads();
  {
    unsigned a0 = h[4*t], a1 = h[4*t+1], a2 = h[4*t+2], a3 = h[4*t+3];
    unsigned p1 = a0 + a1, p2 = p1 + a2, p3 = p2 + a3;
    sc[t] = p3;
    __syncthreads();
    for (int d = 1; d < 256; d <<= 1) {
      unsigned v = (t >= d) ? sc[t - d] : 0u;
      __syncthreads();
      sc[t] += v;
      __syncthreads();
    }
    unsigned ex = sc[t] - p3;
    ls[4*t] = ex;      ls[4*t+1] = ex + a0; ls[4*t+2] = ex + p1; ls[4*t+3] = ex + p2;
    cu[4*t] = ex;      cu[4*t+1] = ex + a0; cu[4*t+2] = ex + p1; cu[4*t+3] = ex + p2;
    gb[4*t]   = a0 ? atomicAdd(&cur_r[4*t],   a0) : 0u;
    gb[4*t+1] = a1 ? atomicAdd(&cur_r[4*t+1], a1) : 0u;
    gb[4*t+2] = a2 ? atomicAdd(&cur_r[4*t+2], a2) : 0u;
    gb[4*t+3] = a3 ? atomicAdd(&cur_r[4*t+3], a3) : 0u;
  }
  __syncthreads();
  #pragma unroll
  for (int u = 0; u < 4; u++) {
    int l0 = 4 * (t + 256 * u);
    #pragma unroll
    for (int j = 0; j < 4; j++) {
      if (l0 + j < cnt) {
        unsigned r = rv[4*u+j], b = r >> BSH;
        unsigned pos = atomicAdd(&cu[b], 1u);
        buf[pos] = ((r & (BSZ - 1u)) << 18) | cv[4*u+j];
        bkt[pos] = (unsigned short)b;
      }
    }
  }
  __syncthreads();
  #pragma unroll
  for (int u = 0; u < 16; u++) {
    int s2 = t + 256 * u;
    if (s2 < cnt) {
      unsigned b = bkt[s2];
      ebuf[gb[b] + ((unsigned)s2 - ls[b])] = buf[s2];
    }
  }
  __syncthreads();

  // ================= COL PASS =================
  for (int i = t; i < NBMAX; i += 256) h[i] = 0;
  __syncthreads();
  #pragma unroll
  for (int u = 0; u < 4; u++) {
    int l0 = 4 * (t + 256 * u);
    #pragma unroll
    for (int j = 0; j < 4; j++)
      if (l0 + j < cnt) atomicAdd(&h[cv[4*u+j] >> BSH], 1u);
  }
  __syncthreads();
  {
    unsigned a0 = h[4*t], a1 = h[4*t+1], a2 = h[4*t+2], a3 = h[4*t+3];
    unsigned p1 = a0 + a1, p2 = p1 + a2, p3 = p2 + a3;
    sc[t] = p3;
    __syncthreads();
    for (int d = 1; d < 256; d <<= 1) {
      unsigned v = (t >= d) ? sc[t - d] : 0u;
      __syncthreads();
      sc[t] += v;
      __syncthreads();
    }
    unsigned ex = sc[t] - p3;
    ls[4*t] = ex;      ls[4*t+1] = ex + a0; ls[4*t+2] = ex + p1; ls[4*t+3] = ex + p2;
    cu[4*t] = ex;      cu[4*t+1] = ex + a0; cu[4*t+2] = ex + p1; cu[4*t+3] = ex + p2;
    gb[4*t]   = a0 ? atomicAdd(&cur_c[4*t],   a0) : 0u;
    gb[4*t+1] = a1 ? atomicAdd(&cur_c[4*t+1], a1) : 0u;
    gb[4*t+2] = a2 ? atomicAdd(&cur_c[4*t+2], a2) : 0u;
    gb[4*t+3] = a3 ? atomicAdd(&cur_c[4*t+3], a3) : 0u;
  }
  __syncthreads();
  #pragma unroll
  for (int u = 0; u < 4; u++) {
    int l0 = 4 * (t + 256 * u);
    #pragma unroll
    for (int j = 0; j < 4; j++) {
      if (l0 + j < cnt) {
        unsigned c = cv[4*u+j], b = c >> BSH;
        unsigned pos = atomicAdd(&cu[b], 1u);
        buf[pos] = c & (BSZ - 1u);
        bkt[pos] = (unsigned short)b;
      }
    }
  }
  __syncthreads();
  #pragma unroll
  for (int u = 0; u < 16; u++) {
    int s2 = t + 256 * u;
    if (s2 < cnt) {
      unsigned b = bkt[s2];
      ebuf2[gb[b] + ((unsigned)s2 - ls[b])] = (unsigned short)buf[s2];
    }
  }
}

// per-bucket degree histogram (LDS), direct write
__global__ void __launch_bounds__(256)
k_degb(const unsigned short* __restrict__ eb, const unsigned* __restrict__ offs,
       const unsigned* __restrict__ tot, unsigned* __restrict__ deg, int N) {
  __shared__ unsigned cnt2[BSZ];
  int b = blockIdx.x, t = threadIdx.x;
  cnt2[t] = 0;
  __syncthreads();
  unsigned s = offs[b], n = tot[b];
  for (unsigned i = t; i < n; i += 256) atomicAdd(&cnt2[eb[s + i]], 1u);
  __syncthreads();
  int node = b * BSZ + t;
  if (node < N) deg[node] = cnt2[t];
}

// ---------------- node MLPs ------------------------------------------------

// mlp1 per node -> h[8]; store hs16 = fp16x8 of dinv * h
__global__ void __launch_bounds__(256)
k_mlp1(const float* __restrict__ x, const unsigned* __restrict__ deg,
       const float* __restrict__ w1, const float* __restrict__ b1,
       const float* __restrict__ w2, const float* __restrict__ b2,
       const float* __restrict__ w3, const float* __restrict__ b3,
       uint4* __restrict__ hs16, int N) {
  __shared__ float sW1[16 * 32], sB1[32], sW2[32 * 16], sB2[16], sW3[16 * 8], sB3[8];
  for (int t = threadIdx.x; t < 512; t += blockDim.x) { sW1[t] = w1[t]; sW2[t] = w2[t]; }
  for (int t = threadIdx.x; t < 128; t += blockDim.x) sW3[t] = w3[t];
  for (int t = threadIdx.x; t < 32; t += blockDim.x) sB1[t] = b1[t];
  for (int t = threadIdx.x; t < 16; t += blockDim.x) sB2[t] = b2[t];
  for (int t = threadIdx.x; t < 8; t += blockDim.x) sB3[t] = b3[t];
  __syncthreads();
  int i = blockIdx.x * blockDim.x + threadIdx.x;
  if (i >= N) return;

  float xin[16];
  const float4* xp = reinterpret_cast<const float4*>(x + (size_t)i * 16);
  #pragma unroll
  for (int q = 0; q < 4; q++) {
    float4 v = xp[q];
    xin[q * 4 + 0] = v.x; xin[q * 4 + 1] = v.y; xin[q * 4 + 2] = v.z; xin[q * 4 + 3] = v.w;
  }
  float h1[32];
  #pragma unroll
  for (int o = 0; o < 32; o++) {
    float s = sB1[o];
    #pragma unroll
    for (int k = 0; k < 16; k++) s = fmaf(xin[k], sW1[k * 32 + o], s);
    h1[o] = fmaxf(s, 0.f);
  }
  float h2[16];
  #pragma unroll
  for (int o = 0; o < 16; o++) {
    float s = sB2[o];
    #pragma unroll
    for (int k = 0; k < 32; k++) s = fmaf(h1[k], sW2[k * 16 + o], s);
    h2[o] = fmaxf(s, 0.f);
  }
  float dinv = rsqrtf((float)(deg[i] + 1u));  // +1 self-loop
  float o0[8];
  #pragma unroll
  for (int o = 0; o < 8; o++) {
    float s = sB3[o];
    #pragma unroll
    for (int k = 0; k < 16; k++) s = fmaf(h2[k], sW3[k * 8 + o], s);
    o0[o] = dinv * s;
  }
  __half2 hh[4];
  #pragma unroll
  for (int q = 0; q < 4; q++) hh[q] = __floats2half2_rn(o0[2 * q], o0[2 * q + 1]);
  hs16[i] = *reinterpret_cast<const uint4*>(hh);
}

// per-bucket: counting sort by rel (LDS), then 1 thread = 1 node register
// accumulation feeding mlp2 directly
__global__ void __launch_bounds__(256)
k_agg(const unsigned* __restrict__ ebuf, const unsigned* __restrict__ offs,
      const unsigned* __restrict__ tot,
      const uint4* __restrict__ hs16, const unsigned* __restrict__ deg,
      const float* __restrict__ w1, const float* __restrict__ b1,
      const float* __restrict__ w2, const float* __restrict__ b2,
      const float* __restrict__ w3, const float* __restrict__ b3,
      float* __restrict__ xn, int N) {
  __shared__ unsigned sorted[TSZ];         // 16KB
  __shared__ unsigned hist[257];
  __shared__ unsigned cum[258];
  __shared__ unsigned cur[257];
  __shared__ unsigned sc[256];
  __shared__ float sW1[256], sB1[32], sW2[512], sB2[16], sW3[256], sB3[16];
  int t = threadIdx.x;
  sW1[t] = w1[t]; sW3[t] = w3[t];
  sW2[t] = w2[t]; sW2[t + 256] = w2[t + 256];
  if (t < 32) sB1[t] = b1[t];
  if (t < 16) { sB2[t] = b2[t]; sB3[t] = b3[t]; }

  int b = blockIdx.x;
  unsigned s = offs[b], n = tot[b];
  unsigned nr = (n + 3u) & ~3u;            // padded region is allocated

  float acc[8];
  #pragma unroll
  for (int c = 0; c < 8; c++) acc[c] = 0.f;

  for (unsigned c0 = 0; c0 < n; c0 += TSZ) {
    if (t < 129) { hist[t] = 0; hist[t + 128] = 0; }
    __syncthreads();

    unsigned rel[16], colv[16];
    #pragma unroll
    for (int u = 0; u < 4; u++) {
      unsigned idx = c0 + 4 * (unsigned)(t + 256 * u);
      uint4 pk = make_uint4(0u, 0u, 0u, 0u);
      if (idx < nr) pk = *reinterpret_cast<const uint4*>(ebuf + s + idx);
      #pragma unroll
      for (int j = 0; j < 4; j++) {
        bool real = (idx + j) < n;
        unsigned p = (&pk.x)[j];
        rel[4*u+j]  = real ? (p >> 18) : 256u;     // 256 = sentinel bin
        colv[4*u+j] = p & 0x3FFFFu;
      }
    }
    #pragma unroll
    for (int u = 0; u < 16; u++) atomicAdd(&hist[rel[u]], 1u);
    __syncthreads();
    unsigned hv = hist[t];
    sc[t] = hv;
    __syncthreads();
    for (int d = 1; d < 256; d <<= 1) {
      unsigned v = (t >= d) ? sc[t - d] : 0u;
      __syncthreads();
      sc[t] += v;
      __syncthreads();
    }
    cum[t] = sc[t] - hv; cur[t] = sc[t] - hv;
    if (t == 255) cum[256] = sc[255];
    __syncthreads();
    #pragma unroll
    for (int u = 0; u < 16; u++) {
      if (rel[u] < 256u) {
        unsigned pos = atomicAdd(&cur[rel[u]], 1u);
        sorted[pos] = colv[u];
      }
    }
    __syncthreads();
    // register accumulation: thread t owns node rel==t (contiguous run)
    unsigned lo = cum[t], hi = cum[t + 1];
    unsigned i = lo;
    for (; i + 4 <= hi; i += 4) {
      unsigned q0 = sorted[i], q1 = sorted[i + 1], q2 = sorted[i + 2], q3 = sorted[i + 3];
      uint4 g0 = hs16[q0];
      uint4 g1 = hs16[q1];
      uint4 g2 = hs16[q2];
      uint4 g3 = hs16[q3];
      addmsg(acc, g0); addmsg(acc, g1); addmsg(acc, g2); addmsg(acc, g3);
    }
    for (; i < hi; i++) { uint4 g = hs16[sorted[i]]; addmsg(acc, g); }
    __syncthreads();
  }

  int node = b * BSZ + t;
  if (node >= N) return;
  float dinv = rsqrtf((float)(deg[node] + 1u));
  uint4 selfp = hs16[node];
  const __half2* sh = reinterpret_cast<const __half2*>(&selfp);
  float a[8];
  #pragma unroll
  for (int q = 0; q < 4; q++) {
    float2 f = __half22float2(sh[q]);
    a[2 * q]     = dinv * (acc[2 * q] + f.x);
    a[2 * q + 1] = dinv * (acc[2 * q + 1] + f.y);
  }

  float h1[32];
  #pragma unroll
  for (int o = 0; o < 32; o++) {
    float v = sB1[o];
    #pragma unroll
    for (int k = 0; k < 8; k++) v = fmaf(a[k], sW1[k * 32 + o], v);
    h1[o] = fmaxf(v, 0.f);
  }
  float h2v[16];
  #pragma unroll
  for (int o = 0; o < 16; o++) {
    float v = sB2[o];
    #pragma unroll
    for (int k = 0; k < 32; k++) v = fmaf(h1[k], sW2[k * 16 + o], v);
    h2v[o] = fmaxf(v, 0.f);
  }
  float o0[16];
  #pragma unroll
  for (int o = 0; o < 16; o++) {
    float v = sB3[o];
    #pragma unroll
    for (int k = 0; k < 16; k++) v = fmaf(h2v[k], sW3[k * 16 + o], v);
    o0[o] = v;
  }
  float4* op = reinterpret_cast<float4*>(xn + (size_t)node * 16);
  #pragma unroll
  for (int q = 0; q < 4; q++)
    op[q] = make_float4(o0[q * 4], o0[q * 4 + 1], o0[q * 4 + 2], o0[q * 4 + 3]);
}

// ---------------- pooling + graph/global MLPs ------------------------------

__global__ void __launch_bounds__(256)
k_pool(const float* __restrict__ x, const float* __restrict__ xn,
       const int* __restrict__ batch, float* __restrict__ pool, int N) {
  int g = blockIdx.x;
  int lo = lowerb(batch, N, g);
  int hi = lowerb(batch, N, g + 1);
  int c = threadIdx.x & 31;
  int j = threadIdx.x >> 5;
  float s = 0.f;
  for (int n = lo + j; n < hi; n += 8) {
    s += (c < 16) ? x[(size_t)n * 16 + c] : xn[(size_t)n * 16 + (c - 16)];
  }
  __shared__ float red[8][33];
  red[j][c] = s;
  __syncthreads();
  if (threadIdx.x < 32) {
    float t = 0.f;
    #pragma unroll
    for (int q = 0; q < 8; q++) t += red[q][threadIdx.x];
    pool[(size_t)g * 32 + threadIdx.x] = t;
  }
}

__global__ void __launch_bounds__(256)
k_dag(const float* __restrict__ pool,
      const float* __restrict__ w1, const float* __restrict__ b1,
      const float* __restrict__ w2, const float* __restrict__ b2,
      const float* __restrict__ w3, const float* __restrict__ b3,
      float* __restrict__ y, int G) {
  __shared__ float sW1[32 * 32], sB1[32], sW2[32 * 16], sB2[16], sW3[16 * 16], sB3[16];
  for (int t = threadIdx.x; t < 1024; t += blockDim.x) sW1[t] = w1[t];
  for (int t = threadIdx.x; t < 512; t += blockDim.x) sW2[t] = w2[t];
  for (int t = threadIdx.x; t < 256; t += blockDim.x) sW3[t] = w3[t];
  for (int t = threadIdx.x; t < 32; t += blockDim.x) sB1[t] = b1[t];
  for (int t = threadIdx.x; t < 16; t += blockDim.x) { sB2[t] = b2[t]; sB3[t] = b3[t]; }
  __syncthreads();
  int g = blockIdx.x * blockDim.x + threadIdx.x;
  if (g >= G) return;

  float in[32];
  const float4* pp = reinterpret_cast<const float4*>(pool + (size_t)g * 32);
  #pragma unroll
  for (int q = 0; q < 8; q++) {
    float4 v = pp[q];
    in[q * 4 + 0] = v.x; in[q * 4 + 1] = v.y; in[q * 4 + 2] = v.z; in[q * 4 + 3] = v.w;
  }
  float h1[32];
  #pragma unroll
  for (int o = 0; o < 32; o++) {
    float s = sB1[o];
    #pragma unroll
    for (int k = 0; k < 32; k++) s = fmaf(in[k], sW1[k * 32 + o], s);
    h1[o] = fmaxf(s, 0.f);
  }
  float h2[16];
  #pragma unroll
  for (int o = 0; o < 16; o++) {
    float s = sB2[o];
    #pragma unroll
    for (int k = 0; k < 32; k++) s = fmaf(h1[k], sW2[k * 16 + o], s);
    h2[o] = fmaxf(s, 0.f);
  }
  float o0[16];
  #pragma unroll
  for (int o = 0; o < 16; o++) {
    float s = sB3[o];
    #pragma unroll
    for (int k = 0; k < 16; k++) s = fmaf(h2[k], sW3[k * 16 + o], s);
    o0[o] = s;
  }
  float4* yp = reinterpret_cast<float4*>(y + (size_t)g * 16);
  #pragma unroll
  for (int q = 0; q < 4; q++)
    yp[q] = make_float4(o0[q * 4], o0[q * 4 + 1], o0[q * 4 + 2], o0[q * 4 + 3]);
}

__global__ void __launch_bounds__(256)
k_z(const float* __restrict__ y,
    const float* __restrict__ w1, const float* __restrict__ b1,
    const float* __restrict__ w2, const float* __restrict__ b2,
    const float* __restrict__ w3, const float* __restrict__ b3,
    float* __restrict__ z, int G) {
  __shared__ float red[16][17];
  __shared__ float sum[16], h1s[32], h2s[16];
  int t = threadIdx.x;
  int c = t & 15, j = t >> 4;
  float s = 0.f;
  for (int g = j; g < G; g += 16) s += y[(size_t)g * 16 + c];
  red[j][c] = s;
  __syncthreads();
  if (t < 16) {
    float v = 0.f;
    #pragma unroll
    for (int q = 0; q < 16; q++) v += red[q][t];
    sum[t] = v;
  }
  __syncthreads();
  if (t < 32) {
    float s1 = b1[t];
    #pragma unroll
    for (int k = 0; k < 16; k++) s1 = fmaf(sum[k], w1[k * 32 + t], s1);
    h1s[t] = fmaxf(s1, 0.f);
  }
  __syncthreads();
  if (t < 16) {
    float s2 = b2[t];
    #pragma unroll
    for (int k = 0; k < 32; k++) s2 = fmaf(h1s[k], w2[k * 16 + t], s2);
    h2s[t] = fmaxf(s2, 0.f);
  }
  __syncthreads();
  if (t < 16) {
    float s3 = b3[t];
    #pragma unroll
    for (int k = 0; k < 16; k++) s3 = fmaf(h2s[k], w3[k * 16 + t], s3);
    z[t] = s3;
  }
}

// ---------------- fallback (known-good atomic path) ------------------------

__global__ void k_deg_atomic(const int* __restrict__ col, unsigned* __restrict__ deg, int E) {
  int e = blockIdx.x * blockDim.x + threadIdx.x;
  if (e < E) atomicAdd(&deg[col[e]], 1u);
}

__global__ void __launch_bounds__(256)
k_mlp1f(const float* __restrict__ x, const unsigned* __restrict__ deg,
        const float* __restrict__ w1, const float* __restrict__ b1,
        const float* __restrict__ w2, const float* __restrict__ b2,
        const float* __restrict__ w3, const float* __restrict__ b3,
        float* __restrict__ hs, int N) {
  __shared__ float sW1[16 * 32], sB1[32], sW2[32 * 16], sB2[16], sW3[16 * 8], sB3[8];
  for (int t = threadIdx.x; t < 512; t += blockDim.x) { sW1[t] = w1[t]; sW2[t] = w2[t]; }
  for (int t = threadIdx.x; t < 128; t += blockDim.x) sW3[t] = w3[t];
  for (int t = threadIdx.x; t < 32; t += blockDim.x) sB1[t] = b1[t];
  for (int t = threadIdx.x; t < 16; t += blockDim.x) sB2[t] = b2[t];
  for (int t = threadIdx.x; t < 8; t += blockDim.x) sB3[t] = b3[t];
  __syncthreads();
  int i = blockIdx.x * blockDim.x + threadIdx.x;
  if (i >= N) return;
  float xin[16];
  const float4* xp = reinterpret_cast<const float4*>(x + (size_t)i * 16);
  #pragma unroll
  for (int q = 0; q < 4; q++) {
    float4 v = xp[q];
    xin[q * 4 + 0] = v.x; xin[q * 4 + 1] = v.y; xin[q * 4 + 2] = v.z; xin[q * 4 + 3] = v.w;
  }
  float h1[32];
  #pragma unroll
  for (int o = 0; o < 32; o++) {
    float s = sB1[o];
    #pragma unroll
    for (int k = 0; k < 16; k++) s = fmaf(xin[k], sW1[k * 32 + o], s);
    h1[o] = fmaxf(s, 0.f);
  }
  float h2[16];
  #pragma unroll
  for (int o = 0; o < 16; o++) {
    float s = sB2[o];
    #pragma unroll
    for (int k = 0; k < 32; k++) s = fmaf(h1[k], sW2[k * 16 + o], s);
    h2[o] = fmaxf(s, 0.f);
  }
  float dinv = rsqrtf((float)(deg[i] + 1u));
  float o0[8];
  #pragma unroll
  for (int o = 0; o < 8; o++) {
    float s = sB3[o];
    #pragma unroll
    for (int k = 0; k < 16; k++) s = fmaf(h2[k], sW3[k * 8 + o], s);
    o0[o] = dinv * s;
  }
  float4* hp = reinterpret_cast<float4*>(hs + (size_t)i * 8);
  hp[0] = make_float4(o0[0], o0[1], o0[2], o0[3]);
  hp[1] = make_float4(o0[4], o0[5], o0[6], o0[7]);
}

__global__ void k_scatter_atomic(const int* __restrict__ row, const int* __restrict__ col,
                                 const float* __restrict__ hs, float* __restrict__ acc, int E) {
  int e = blockIdx.x * blockDim.x + threadIdx.x;
  if (e >= E) return;
  int r = row[e], c = col[e];
  const float4* hp = reinterpret_cast<const float4*>(hs + (size_t)c * 8);
  float4 a = hp[0], b = hp[1];
  float* ap = acc + (size_t)r * 8;
  atomicAdd(ap + 0, a.x); atomicAdd(ap + 1, a.y);
  atomicAdd(ap + 2, a.z); atomicAdd(ap + 3, a.w);
  atomicAdd(ap + 4, b.x); atomicAdd(ap + 5, b.y);
  atomicAdd(ap + 6, b.z); atomicAdd(ap + 7, b.w);
}

__global__ void __launch_bounds__(256)
k_finalize(const float* __restrict__ hs, const float* __restrict__ acc,
           const unsigned* __restrict__ deg,
           const float* __restrict__ w1, const float* __restrict__ b1,
           const float* __restrict__ w2, const float* __restrict__ b2,
           const float* __restrict__ w3, const float* __restrict__ b3,
           float* __restrict__ xn, int N) {
  __shared__ float sW1[8 * 32], sB1[32], sW2[32 * 16], sB2[16], sW3[16 * 16], sB3[16];
  for (int t = threadIdx.x; t < 256; t += blockDim.x) { sW1[t] = w1[t]; sW3[t] = w3[t]; }
  for (int t = threadIdx.x; t < 512; t += blockDim.x) sW2[t] = w2[t];
  for (int t = threadIdx.x; t < 32; t += blockDim.x) sB1[t] = b1[t];
  for (int t = threadIdx.x; t < 16; t += blockDim.x) { sB2[t] = b2[t]; sB3[t] = b3[t]; }
  __syncthreads();
  int i = blockIdx.x * blockDim.x + threadIdx.x;
  if (i >= N) return;
  float dinv = rsqrtf((float)(deg[i] + 1u));
  float a[8];
  const float4* accp = reinterpret_cast<const float4*>(acc + (size_t)i * 8);
  const float4* hsp = reinterpret_cast<const float4*>(hs + (size_t)i * 8);
  float4 a0 = accp[0], a1 = accp[1], s0 = hsp[0], s1 = hsp[1];
  a[0] = dinv * (a0.x + s0.x); a[1] = dinv * (a0.y + s0.y);
  a[2] = dinv * (a0.z + s0.z); a[3] = dinv * (a0.w + s0.w);
  a[4] = dinv * (a1.x + s1.x); a[5] = dinv * (a1.y + s1.y);
  a[6] = dinv * (a1.z + s1.z); a[7] = dinv * (a1.w + s1.w);
  float h1[32];
  #pragma unroll
  for (int o = 0; o < 32; o++) {
    float s = sB1[o];
    #pragma unroll
    for (int k = 0; k < 8; k++) s = fmaf(a[k], sW1[k * 32 + o], s);
    h1[o] = fmaxf(s, 0.f);
  }
  float h2[16];
  #pragma unroll
  for (int o = 0; o < 16; o++) {
    float s = sB2[o];
    #pragma unroll
    for (int k = 0; k < 32; k++) s = fmaf(h1[k], sW2[k * 16 + o], s);
    h2[o] = fmaxf(s, 0.f);
  }
  float o0[16];
  #pragma unroll
  for (int o = 0; o < 16; o++) {
    float s = sB3[o];
    #pragma unroll
    for (int k = 0; k < 16; k++) s = fmaf(h2[k], sW3[k * 16 + o], s);
    o0[o] = s;
  }
  float4* op = reinterpret_cast<float4*>(xn + (size_t)i * 16);
  #pragma unroll
  for (int q = 0; q < 4; q++)
    op[q] = make_float4(o0[q * 4], o0[q * 4 + 1], o0[q * 4 + 2], o0[q * 4 + 3]);
}

// ---------------------------------------------------------------------------

extern "C" void kernel_launch(void* const* d_in, const int* in_sizes, int n_in,
                              void* d_out, int out_size, void* d_ws, size_t ws_size,
                              hipStream_t stream) {
  const float* x = (const float*)d_in[0];
  const int* ei = (const int*)d_in[1];
  const int* batch = (const int*)d_in[2];
  const float* m1w1 = (const float*)d_in[4];  const float* m1b1 = (const float*)d_in[5];
  const float* m1w2 = (const float*)d_in[6];  const float* m1b2 = (const float*)d_in[7];
  const float* m1w3 = (const float*)d_in[8];  const float* m1b3 = (const float*)d_in[9];
  const float* m2w1 = (const float*)d_in[10]; const float* m2b1 = (const float*)d_in[11];
  const float* m2w2 = (const float*)d_in[12]; const float* m2b2 = (const float*)d_in[13];
  const float* m2w3 = (const float*)d_in[14]; const float* m2b3 = (const float*)d_in[15];
  const float* mdw1 = (const float*)d_in[16]; const float* mdb1 = (const float*)d_in[17];
  const float* mdw2 = (const float*)d_in[18]; const float* mdb2 = (const float*)d_in[19];
  const float* mdw3 = (const float*)d_in[20]; const float* mdb3 = (const float*)d_in[21];
  const float* mgw1 = (const float*)d_in[22]; const float* mgb1 = (const float*)d_in[23];
  const float* mgw2 = (const float*)d_in[24]; const float* mgb2 = (const float*)d_in[25];
  const float* mgw3 = (const float*)d_in[26]; const float* mgb3 = (const float*)d_in[27];

  int N = in_sizes[0] / 16;
  int E = in_sizes[1] / 2;
  int G = (out_size - N * 16 - 16) / 16;
  const int* rowp = ei;       // aggregation (destination) index
  const int* colp = ei + E;   // message source index

  float* xn = (float*)d_out;
  float* yv = xn + (size_t)N * 16;
  float* zv = yv + (size_t)G * 16;

  int nb = (N + BSZ - 1) / BSZ;

  size_t off = 0;
  auto alloc = [&](size_t bytes) -> size_t {
    off = (off + 255) & ~(size_t)255;
    size_t o = off; off += bytes; return o;
  };
  char* ws = (char*)d_ws;
  size_t o_deg  = alloc((size_t)N * 4);
  size_t o_hs16 = alloc((size_t)N * 16);
  size_t o_bkt  = alloc((size_t)6 * NBMAX * 4);
  size_t o_eb   = alloc(((size_t)E + 4 * NBMAX) * 4);   // padded row buckets
  size_t o_eb2  = alloc((size_t)E * 2);
  size_t o_pool = alloc((size_t)G * 32 * 4);
  size_t need = off;

  bool bucketed = (ws_size >= need) && (nb <= NBMAX) && (N <= (1 << 18));

  if (bucketed) {
    unsigned* deg = (unsigned*)(ws + o_deg);
    uint4* hs16 = (uint4*)(ws + o_hs16);
    unsigned* tot_r  = (unsigned*)(ws + o_bkt);
    unsigned* offs_r = tot_r + NBMAX;
    unsigned* cur_r  = tot_r + 2 * NBMAX;
    unsigned* tot_c  = tot_r + 3 * NBMAX;
    unsigned* offs_c = tot_r + 4 * NBMAX;
    unsigned* cur_c  = tot_r + 5 * NBMAX;
    unsigned* ebuf = (unsigned*)(ws + o_eb);
    unsigned short* ebuf2 = (unsigned short*)(ws + o_eb2);
    float* pool = (float*)(ws + o_pool);

    hipMemsetAsync(ws + o_bkt, 0, (size_t)6 * NBMAX * 4, stream);

    int NT = (E + TSZ - 1) / TSZ;
    k_count2<<<1024, 256, 0, stream>>>(rowp, colp, E, nb, tot_r, tot_c);
    k_scan2<<<2, 1024, 0, stream>>>(tot_r, offs_r, cur_r, tot_c, offs_c, cur_c, nb);
    k_scat2<<<NT, 256, 0, stream>>>(rowp, colp, E, nb, cur_r, cur_c, ebuf, ebuf2);
    k_degb<<<nb, 256, 0, stream>>>(ebuf2, offs_c, tot_c, deg, N);

    k_mlp1<<<(N + 255) / 256, 256, 0, stream>>>(x, deg, m1w1, m1b1, m1w2, m1b2, m1w3, m1b3, hs16, N);
    k_agg<<<nb, 256, 0, stream>>>(ebuf, offs_r, tot_r, hs16, deg,
                                  m2w1, m2b1, m2w2, m2b2, m2w3, m2b3, xn, N);

    k_pool<<<G, 256, 0, stream>>>(x, xn, batch, pool, N);
    k_dag<<<(G + 255) / 256, 256, 0, stream>>>(pool, mdw1, mdb1, mdw2, mdb2, mdw3, mdb3, yv, G);
    k_z<<<1, 256, 0, stream>>>(yv, mgw1, mgb1, mgw2, mgb2, mgw3, mgb3, zv, G);
  } else {
    unsigned* deg = (unsigned*)ws;
    float* acc = (float*)(ws + (size_t)N * 4);
    float* hs  = (float*)(ws + (size_t)N * 36);
    float* pool = (float*)(ws + (size_t)N * 68);

    hipMemsetAsync(ws, 0, (size_t)N * 36, stream);
    const int TB = 256;
    k_deg_atomic<<<(E + TB - 1) / TB, TB, 0, stream>>>(colp, deg, E);
    k_mlp1f<<<(N + TB - 1) / TB, TB, 0, stream>>>(x, deg, m1w1, m1b1, m1w2, m1b2, m1w3, m1b3, hs, N);
    k_scatter_atomic<<<(E + TB - 1) / TB, TB, 0, stream>>>(rowp, colp, hs, acc, E);
    k_finalize<<<(N + TB - 1) / TB, TB, 0, stream>>>(hs, acc, deg, m2w1, m2b1, m2w2, m2b2, m2w3, m2b3, xn, N);
    k_pool<<<G, TB, 0, stream>>>(x, xn, batch, pool, N);
    k_dag<<<(G + TB - 1) / TB, TB, 0, stream>>>(pool, mdw1, mdb1, mdw2, mdb2, mdw3, mdb3, yv, G);
    k_z<<<1, TB, 0, stream>>>(yv, mgw1, mgb1, mgw2, mgb2, mgw3, mgb3, zv, G);
  }
}